// Round 1
// baseline (2107.350 us; speedup 1.0000x reference)
//
#include <hip/hip_runtime.h>
#include <hip/hip_bf16.h>
#include <math.h>

// Shapes (fixed by setup_inputs): B=2, S=1024, H=2048, nheads=16, d=128
#define B_  2
#define S_  1024
#define H_  2048
#define NH_ 16
#define D_  128
#define BS_ (B_ * S_)          // 2048 rows
#define ROWLEN H_              // 2048

// ---------------------------------------------------------------------------
// xPos tables: sin/cos/scale, each [S][64]
// ---------------------------------------------------------------------------
__global__ void tables_kernel(float* __restrict__ sinT, float* __restrict__ cosT,
                              float* __restrict__ scaleT) {
    int idx = blockIdx.x * 256 + threadIdx.x;   // 0 .. 65535
    int s = idx >> 6, j = idx & 63;
    float xscale   = (2.0f * j + 0.4f * 128.0f) / (1.4f * 128.0f);
    float sc       = powf(xscale, (float)s * (1.0f / 512.0f));
    float inv_freq = powf(10000.0f, -(float)j * (1.0f / 64.0f));
    float ang      = (float)s * inv_freq;
    sinT[idx]   = sinf(ang);
    cosT[idx]   = cosf(ang);
    scaleT[idx] = sc;
}

// ---------------------------------------------------------------------------
// Tiled fp32 GEMM: C[M x N] = A[M x K] * B[K x N]
// headed=1: B is (nheads, K, 128) per-head packing (W_Q/W_K/W_V layout)
// headed=0: B is plain row-major K x N
// 64x64 tile, BK=16, 256 threads, 4x4 accum/thread.
// ---------------------------------------------------------------------------
__global__ __launch_bounds__(256) void gemm_kernel(
    const float* __restrict__ A, const float* __restrict__ Bm,
    float* __restrict__ C, int M, int N, int Kdim, int headed) {
    __shared__ float As[16][68];
    __shared__ float Bs[16][68];

    int tid = threadIdx.x;
    int tx = tid & 15, ty = tid >> 4;
    int col0 = blockIdx.x * 64, row0 = blockIdx.y * 64;

    const float* Bbase;
    int ldB, dc0;
    if (headed) {
        int head = col0 >> 7;
        Bbase = Bm + (size_t)head * Kdim * 128;
        ldB = 128;
        dc0 = col0 & 127;
    } else {
        Bbase = Bm;
        ldB = N;
        dc0 = col0;
    }

    float acc[4][4] = {};

    int ar = tid >> 2, ak = (tid & 3) * 4;     // A-tile load coords
    int bk = tid >> 4, bc = (tid & 15) * 4;    // B-tile load coords

    for (int k0 = 0; k0 < Kdim; k0 += 16) {
        float4 av = *(const float4*)&A[(size_t)(row0 + ar) * Kdim + k0 + ak];
        float4 bv = *(const float4*)&Bbase[(size_t)(k0 + bk) * ldB + dc0 + bc];
        As[ak + 0][ar] = av.x;
        As[ak + 1][ar] = av.y;
        As[ak + 2][ar] = av.z;
        As[ak + 3][ar] = av.w;
        *(float4*)&Bs[bk][bc] = bv;
        __syncthreads();
#pragma unroll
        for (int kk = 0; kk < 16; ++kk) {
            float4 a = *(const float4*)&As[kk][ty * 4];
            float4 b = *(const float4*)&Bs[kk][tx * 4];
            acc[0][0] += a.x * b.x; acc[0][1] += a.x * b.y; acc[0][2] += a.x * b.z; acc[0][3] += a.x * b.w;
            acc[1][0] += a.y * b.x; acc[1][1] += a.y * b.y; acc[1][2] += a.y * b.z; acc[1][3] += a.y * b.w;
            acc[2][0] += a.z * b.x; acc[2][1] += a.z * b.y; acc[2][2] += a.z * b.z; acc[2][3] += a.z * b.w;
            acc[3][0] += a.w * b.x; acc[3][1] += a.w * b.y; acc[3][2] += a.w * b.z; acc[3][3] += a.w * b.w;
        }
        __syncthreads();
    }
#pragma unroll
    for (int i = 0; i < 4; ++i) {
        float4 v = make_float4(acc[i][0], acc[i][1], acc[i][2], acc[i][3]);
        *(float4*)&C[(size_t)(row0 + ty * 4 + i) * N + col0 + tx * 4] = v;
    }
}

// ---------------------------------------------------------------------------
// xPos rotary: applied in-place to Q (scale) and K (1/scale).
// Layout: [b*S+s][n*128 + c]; tables indexed [s*64 + j], pair j = (c%128)/2.
// Each thread handles one float4 = 2 rotary pairs.
// ---------------------------------------------------------------------------
__global__ void xpos_kernel(float* __restrict__ Q, float* __restrict__ K,
                            const float* __restrict__ sinT,
                            const float* __restrict__ cosT,
                            const float* __restrict__ scaleT) {
    int chunk = blockIdx.x * 256 + threadIdx.x;   // 0 .. 1048575
    int which = blockIdx.y;                        // 0=Q, 1=K
    int row = chunk >> 9;                          // 512 float4 per row
    int c = (chunk & 511) << 2;
    int s = row & (S_ - 1);
    int hc = c & 127;
    int j = hc >> 1;
    float* ptr = which ? K : Q;
    float4 x = *(float4*)&ptr[(size_t)row * ROWLEN + c];
    int tb = s * 64 + j;
    float sc0 = scaleT[tb], sc1 = scaleT[tb + 1];
    if (which) { sc0 = 1.0f / sc0; sc1 = 1.0f / sc1; }
    float c0 = cosT[tb] * sc0,     s0 = sinT[tb] * sc0;
    float c1 = cosT[tb + 1] * sc1, s1 = sinT[tb + 1] * sc1;
    float4 y;
    y.x = x.x * c0 - x.y * s0;
    y.y = x.y * c0 + x.x * s0;
    y.z = x.z * c1 - x.w * s1;
    y.w = x.w * c1 + x.z * s1;
    *(float4*)&ptr[(size_t)row * ROWLEN + c] = y;
}

// ---------------------------------------------------------------------------
// Retention: per (b, n): Y[s,:] = sum_{t<=s} gamma^(s-t) * (q_s . k_t) * v_t
// Block = (sTile of 32 rows, bn). 256 threads.
// ---------------------------------------------------------------------------
__global__ __launch_bounds__(256) void retention_kernel(
    const float* __restrict__ Q, const float* __restrict__ K,
    const float* __restrict__ V, float* __restrict__ Y) {
    __shared__ float Qs[32][132];
    __shared__ float Ks[32][132];
    __shared__ float Vs[32][132];
    __shared__ float Ss[32][33];

    int sTile = blockIdx.x;
    int bn = blockIdx.y;
    int b = bn >> 4, n = bn & 15;
    int s0 = sTile * 32;
    int tid = threadIdx.x;

    const float l0 = -3.4657359027997265f;  // ln(1/32)
    const float l1 = -6.2383246250395077f;  // ln(1/512)
    float gamma = 1.0f - expf(l0 + (l1 - l0) * (float)n * (1.0f / 15.0f));
    float log2g = log2f(gamma);

    // load Q tile
    const float* Qbase = Q + (size_t)(b * S_ + s0) * ROWLEN + n * 128;
    for (int it = 0; it < 4; ++it) {
        int f4 = it * 256 + tid;
        int r = f4 >> 5;
        int c4 = (f4 & 31) * 4;
        *(float4*)&Qs[r][c4] = *(const float4*)&Qbase[(size_t)r * ROWLEN + c4];
    }

    float yacc[16];
#pragma unroll
    for (int i = 0; i < 16; ++i) yacc[i] = 0.0f;

    int r  = tid >> 3;            // row within tile
    int tb = (tid & 7) * 4;       // S columns owned (4)
    int c0 = (tid & 7) * 16;      // Y columns owned (16)

    for (int t0 = 0; t0 <= s0; t0 += 32) {
        __syncthreads();  // protect Ks/Vs reuse + first-iter Qs visibility... (store->load fence below)
        const float* Kbase = K + (size_t)(b * S_ + t0) * ROWLEN + n * 128;
        const float* Vbase = V + (size_t)(b * S_ + t0) * ROWLEN + n * 128;
        for (int it = 0; it < 4; ++it) {
            int f4 = it * 256 + tid;
            int rr = f4 >> 5;
            int c4 = (f4 & 31) * 4;
            *(float4*)&Ks[rr][c4] = *(const float4*)&Kbase[(size_t)rr * ROWLEN + c4];
            *(float4*)&Vs[rr][c4] = *(const float4*)&Vbase[(size_t)rr * ROWLEN + c4];
        }
        __syncthreads();

        // S tile: each thread 4 dot products (row r, cols tb..tb+3)
        float acc[4] = {0.0f, 0.0f, 0.0f, 0.0f};
#pragma unroll 8
        for (int k4 = 0; k4 < 32; ++k4) {
            float4 qv = *(const float4*)&Qs[r][k4 * 4];
#pragma unroll
            for (int q = 0; q < 4; ++q) {
                float4 kv = *(const float4*)&Ks[tb + q][k4 * 4];
                acc[q] += qv.x * kv.x + qv.y * kv.y + qv.z * kv.z + qv.w * kv.w;
            }
        }
#pragma unroll
        for (int q = 0; q < 4; ++q) {
            int dt = (s0 + r) - (t0 + tb + q);
            float w = (dt < 0) ? 0.0f : exp2f((float)dt * log2g);
            Ss[r][tb + q] = acc[q] * w;
        }
        __syncthreads();

        // PV: Y[r, c0..c0+15] += sum_t Ss[r][t] * Vs[t][...]
#pragma unroll 8
        for (int t = 0; t < 32; ++t) {
            float w = Ss[r][t];
#pragma unroll
            for (int c4 = 0; c4 < 4; ++c4) {
                float4 vv = *(const float4*)&Vs[t][c0 + c4 * 4];
                yacc[c4 * 4 + 0] += w * vv.x;
                yacc[c4 * 4 + 1] += w * vv.y;
                yacc[c4 * 4 + 2] += w * vv.z;
                yacc[c4 * 4 + 3] += w * vv.w;
            }
        }
    }

    float* Ybase = Y + (size_t)(b * S_ + s0) * ROWLEN + n * 128;
#pragma unroll
    for (int c4 = 0; c4 < 4; ++c4) {
        float4 v = make_float4(yacc[c4 * 4 + 0], yacc[c4 * 4 + 1],
                               yacc[c4 * 4 + 2], yacc[c4 * 4 + 3]);
        *(float4*)&Ybase[(size_t)r * ROWLEN + c0 + c4 * 4] = v;
    }
}

// ---------------------------------------------------------------------------
// GroupNorm (16 groups of 128) + SiLU gate, one block per (b,s) row.
// Z = (gn_w * (Y-mu)/sqrt(var+eps) + gn_b) * (G * sigmoid(G))
// ---------------------------------------------------------------------------
__global__ __launch_bounds__(256) void gn_gate_kernel(
    const float* __restrict__ Y, const float* __restrict__ G,
    const float* __restrict__ gnw, const float* __restrict__ gnb,
    float* __restrict__ Z) {
    int row = blockIdx.x;
    int lane = threadIdx.x & 63;
    int wave = threadIdx.x >> 6;
    const float* yrow = Y + (size_t)row * ROWLEN;
    const float* grow = G + (size_t)row * ROWLEN;
    float* zrow = Z + (size_t)row * ROWLEN;

    for (int g = wave * 4; g < wave * 4 + 4; ++g) {
        float y0 = yrow[g * 128 + lane];
        float y1 = yrow[g * 128 + 64 + lane];
        float sum = y0 + y1;
#pragma unroll
        for (int m = 32; m >= 1; m >>= 1) sum += __shfl_xor(sum, m, 64);
        float mean = sum * (1.0f / 128.0f);
        float d0 = y0 - mean, d1 = y1 - mean;
        float vs = d0 * d0 + d1 * d1;
#pragma unroll
        for (int m = 32; m >= 1; m >>= 1) vs += __shfl_xor(vs, m, 64);
        float rinv = rsqrtf(vs * (1.0f / 128.0f) + 1e-5f);
        int h0 = g * 128 + lane, h1 = h0 + 64;
        float yn0 = d0 * rinv * gnw[h0] + gnb[h0];
        float yn1 = d1 * rinv * gnw[h1] + gnb[h1];
        float gv0 = grow[h0], gv1 = grow[h1];
        float gate0 = gv0 / (1.0f + expf(-gv0));
        float gate1 = gv1 / (1.0f + expf(-gv1));
        zrow[h0] = gate0 * yn0;
        zrow[h1] = gate1 * yn1;
    }
}

// ---------------------------------------------------------------------------
extern "C" void kernel_launch(void* const* d_in, const int* in_sizes, int n_in,
                              void* d_out, int out_size, void* d_ws, size_t ws_size,
                              hipStream_t stream) {
    const float* X   = (const float*)d_in[0];
    const float* W_Q = (const float*)d_in[1];
    const float* W_K = (const float*)d_in[2];
    const float* W_V = (const float*)d_in[3];
    const float* W_G = (const float*)d_in[4];
    const float* W_O = (const float*)d_in[5];
    const float* gnw = (const float*)d_in[6];
    const float* gnb = (const float*)d_in[7];
    float* out = (float*)d_out;
    float* ws  = (float*)d_ws;

    const size_t MAT = (size_t)BS_ * H_;   // 4,194,304 floats
    float* Qb = ws;
    float* Kb = ws + MAT;
    float* Vb = ws + 2 * MAT;
    float* Gb = ws + 3 * MAT;
    float* Yb = ws + 4 * MAT;
    float* sinT   = ws + 5 * MAT;
    float* cosT   = sinT + S_ * 64;
    float* scaleT = cosT + S_ * 64;
    float* Zb = Qb;  // Q dead after retention; reuse for gated output

    tables_kernel<<<256, 256, 0, stream>>>(sinT, cosT, scaleT);

    dim3 gg(32, 32);
    gemm_kernel<<<gg, 256, 0, stream>>>(X, W_Q, Qb, BS_, H_, H_, 1);
    gemm_kernel<<<gg, 256, 0, stream>>>(X, W_K, Kb, BS_, H_, H_, 1);
    gemm_kernel<<<gg, 256, 0, stream>>>(X, W_V, Vb, BS_, H_, H_, 1);
    gemm_kernel<<<gg, 256, 0, stream>>>(X, W_G, Gb, BS_, H_, H_, 0);

    xpos_kernel<<<dim3(4096, 2), 256, 0, stream>>>(Qb, Kb, sinT, cosT, scaleT);

    retention_kernel<<<dim3(32, 32), 256, 0, stream>>>(Qb, Kb, Vb, Yb);

    gn_gate_kernel<<<BS_, 256, 0, stream>>>(Yb, Gb, gnw, gnb, Zb);

    gemm_kernel<<<gg, 256, 0, stream>>>(Zb, W_O, out, BS_, H_, H_, 0);
}

// Round 2
// 1118.019 us; speedup vs baseline: 1.8849x; 1.8849x over previous
//
#include <hip/hip_runtime.h>
#include <math.h>

// Shapes (fixed): B=2, S=1024, H=2048, nheads=16, d=128
#define S_     1024
#define H_     2048
#define BS_    2048
#define ROWLEN 2048
#define MATF   ((size_t)BS_ * H_)    // elements per 2048x2048 matrix

typedef __bf16 bf16x8 __attribute__((ext_vector_type(8)));
typedef float  f32x4  __attribute__((ext_vector_type(4)));

__device__ __forceinline__ void f2hilo(float x, short& h, short& l) {
    __bf16 bh = (__bf16)x;
    float  r  = x - (float)bh;
    __bf16 bl = (__bf16)r;
    h = __builtin_bit_cast(short, bh);
    l = __builtin_bit_cast(short, bl);
}

__device__ __forceinline__ void gload16(const void* g, void* l) {
    __builtin_amdgcn_global_load_lds(
        (const __attribute__((address_space(1))) void*)g,
        (__attribute__((address_space(3))) void*)l, 16, 0, 0);
}

// ---------------------------------------------------------------------------
// xPos tables: sin/cos/scale, each [S][64]
// ---------------------------------------------------------------------------
__global__ void tables_kernel(float* __restrict__ sinT, float* __restrict__ cosT,
                              float* __restrict__ scaleT) {
    int idx = blockIdx.x * 256 + threadIdx.x;   // 0 .. 65535
    int s = idx >> 6, j = idx & 63;
    float xscale   = (2.0f * j + 0.4f * 128.0f) / (1.4f * 128.0f);
    float sc       = powf(xscale, (float)s * (1.0f / 512.0f));
    float inv_freq = powf(10000.0f, -(float)j * (1.0f / 64.0f));
    float ang      = (float)s * inv_freq;
    sinT[idx]   = sinf(ang);
    cosT[idx]   = cosf(ang);
    scaleT[idx] = sc;
}

// ---------------------------------------------------------------------------
// fp32 -> bf16 hi/lo split, elementwise (A operands, row-major preserved)
// ---------------------------------------------------------------------------
__global__ __launch_bounds__(256) void cvt_hilo_kernel(
    const float* __restrict__ src, short* __restrict__ hi, short* __restrict__ lo) {
    int i = blockIdx.x * 256 + threadIdx.x;     // one float4
    float4 v = *(const float4*)&src[(size_t)i * 4];
    short h[4], l[4];
    f2hilo(v.x, h[0], l[0]);
    f2hilo(v.y, h[1], l[1]);
    f2hilo(v.z, h[2], l[2]);
    f2hilo(v.w, h[3], l[3]);
    *(short4*)&hi[(size_t)i * 4] = make_short4(h[0], h[1], h[2], h[3]);
    *(short4*)&lo[(size_t)i * 4] = make_short4(l[0], l[1], l[2], l[3]);
}

// ---------------------------------------------------------------------------
// Weight -> transposed bf16 hi/lo: Wt[n][k] = W[k][n]  (Bt layout for MFMA)
// headed=1: W is (16, 2048, 128), n_global = head*128 + d
// headed=0: W is (2048, 2048) row-major [k][n]
// Block: 32(k) x 32(n) tile, 256 threads.
// ---------------------------------------------------------------------------
__global__ __launch_bounds__(256) void cvtWt_kernel(
    const float* __restrict__ W, short* __restrict__ hi, short* __restrict__ lo,
    int headed) {
    __shared__ float T[32][33];
    int k0 = blockIdx.x * 32, n0 = blockIdx.y * 32;
    int tx = threadIdx.x & 7, ty = threadIdx.x >> 3;   // ty: k-row 0..31, tx*4: n
    const float* src;
    if (headed) {
        int head = n0 >> 7, d0 = n0 & 127;
        src = W + ((size_t)head * 2048 + (k0 + ty)) * 128 + d0 + tx * 4;
    } else {
        src = W + (size_t)(k0 + ty) * 2048 + n0 + tx * 4;
    }
    float4 v = *(const float4*)src;
    T[ty][tx * 4 + 0] = v.x;
    T[ty][tx * 4 + 1] = v.y;
    T[ty][tx * 4 + 2] = v.z;
    T[ty][tx * 4 + 3] = v.w;
    __syncthreads();
    int nl = ty, k4 = tx * 4;
    short h[4], l[4];
#pragma unroll
    for (int j = 0; j < 4; ++j) f2hilo(T[k4 + j][nl], h[j], l[j]);
    size_t off = (size_t)(n0 + nl) * 2048 + k0 + k4;
    *(short4*)&hi[off] = make_short4(h[0], h[1], h[2], h[3]);
    *(short4*)&lo[off] = make_short4(l[0], l[1], l[2], l[3]);
}

// ---------------------------------------------------------------------------
// Split-bf16 MFMA GEMM: C[2048][2048] fp32 = (Ahi+Alo) * (Bhi+Blo)^T(stored Bt)
// A: [M][K] bf16 row-major; Bt: [N][K] bf16 row-major.
// 128x128 tile, BK=32, 256 threads (4 waves, 2x2), 16x16x32 MFMA x3 terms.
// LDS fragment-ordered: seg[kblk(4)][row(128)][8 bf16] -> conflict-free b128.
// ---------------------------------------------------------------------------
__global__ __launch_bounds__(256) void mfma_gemm_kernel(
    const short* __restrict__ Ahi, const short* __restrict__ Alo,
    const short* __restrict__ Bhi, const short* __restrict__ Blo,
    float* __restrict__ C) {
    __shared__ short lds[4 * 4096];   // Ahi | Alo | Bhi | Blo, 8KB each

    int tid = threadIdx.x;
    int w = tid >> 6, l = tid & 63;

    // XCD-aware swizzle (256 wgs, 8 XCDs, bijective)
    int bid = blockIdx.y * 16 + blockIdx.x;
    bid = (bid & 7) * 32 + (bid >> 3);
    int row0 = (bid >> 4) * 128, col0 = (bid & 15) * 128;

    int wr = w >> 1, wc = w & 1;

    f32x4 acc[4][4] = {};

    // staging: entry e = i*256+tid -> kblk=e>>7, row=e&127; 16B per entry
    int e0 = tid, e1 = 256 + tid;
    int kb0 = e0 >> 7, rr0 = e0 & 127;
    int kb1 = e1 >> 7, rr1 = e1 & 127;
    const short* pa0h = Ahi + (size_t)(row0 + rr0) * 2048 + kb0 * 8;
    const short* pa1h = Ahi + (size_t)(row0 + rr1) * 2048 + kb1 * 8;
    const short* pa0l = Alo + (size_t)(row0 + rr0) * 2048 + kb0 * 8;
    const short* pa1l = Alo + (size_t)(row0 + rr1) * 2048 + kb1 * 8;
    const short* pb0h = Bhi + (size_t)(col0 + rr0) * 2048 + kb0 * 8;
    const short* pb1h = Bhi + (size_t)(col0 + rr1) * 2048 + kb1 * 8;
    const short* pb0l = Blo + (size_t)(col0 + rr0) * 2048 + kb0 * 8;
    const short* pb1l = Blo + (size_t)(col0 + rr1) * 2048 + kb1 * 8;
    short* lA0 = &lds[0 * 4096 + w * 512];        // wave-uniform bases
    short* lA1 = &lds[0 * 4096 + (4 + w) * 512];
    short* lAl0 = &lds[1 * 4096 + w * 512];
    short* lAl1 = &lds[1 * 4096 + (4 + w) * 512];
    short* lB0 = &lds[2 * 4096 + w * 512];
    short* lB1 = &lds[2 * 4096 + (4 + w) * 512];
    short* lBl0 = &lds[3 * 4096 + w * 512];
    short* lBl1 = &lds[3 * 4096 + (4 + w) * 512];

    int lr = l & 15, lk = l >> 4;
    int abase = (lk << 10) + (wr << 9) + (lr << 3);   // + m*128
    int bbase = (lk << 10) + (wc << 9) + (lr << 3);   // + n*128

    for (int k0 = 0; k0 < 2048; k0 += 32) {
        gload16(pa0h + k0, lA0);
        gload16(pa1h + k0, lA1);
        gload16(pa0l + k0, lAl0);
        gload16(pa1l + k0, lAl1);
        gload16(pb0h + k0, lB0);
        gload16(pb1h + k0, lB1);
        gload16(pb0l + k0, lBl0);
        gload16(pb1l + k0, lBl1);
        __syncthreads();

        bf16x8 ah[4], al[4], bh[4], bl[4];
#pragma unroll
        for (int m = 0; m < 4; ++m) {
            ah[m] = *(const bf16x8*)&lds[0 * 4096 + abase + m * 128];
            al[m] = *(const bf16x8*)&lds[1 * 4096 + abase + m * 128];
        }
#pragma unroll
        for (int n = 0; n < 4; ++n) {
            bh[n] = *(const bf16x8*)&lds[2 * 4096 + bbase + n * 128];
            bl[n] = *(const bf16x8*)&lds[3 * 4096 + bbase + n * 128];
        }
#pragma unroll
        for (int m = 0; m < 4; ++m)
#pragma unroll
            for (int n = 0; n < 4; ++n) {
                acc[m][n] = __builtin_amdgcn_mfma_f32_16x16x32_bf16(ah[m], bh[n], acc[m][n], 0, 0, 0);
                acc[m][n] = __builtin_amdgcn_mfma_f32_16x16x32_bf16(ah[m], bl[n], acc[m][n], 0, 0, 0);
                acc[m][n] = __builtin_amdgcn_mfma_f32_16x16x32_bf16(al[m], bh[n], acc[m][n], 0, 0, 0);
            }
        __syncthreads();
    }

    // C/D layout: col = lane&15, row = (lane>>4)*4 + i
#pragma unroll
    for (int m = 0; m < 4; ++m)
#pragma unroll
        for (int n = 0; n < 4; ++n) {
            int row = row0 + (wr << 6) + (m << 4) + (lk << 2);
            int col = col0 + (wc << 6) + (n << 4) + lr;
            float* cp = &C[(size_t)row * 2048 + col];
            cp[0 * 2048] = acc[m][n][0];
            cp[1 * 2048] = acc[m][n][1];
            cp[2 * 2048] = acc[m][n][2];
            cp[3 * 2048] = acc[m][n][3];
        }
}

// ---------------------------------------------------------------------------
// xPos rotary in-place on fp32 Q (scale) / K (1/scale)
// ---------------------------------------------------------------------------
__global__ void xpos_kernel(float* __restrict__ Q, float* __restrict__ K,
                            const float* __restrict__ sinT,
                            const float* __restrict__ cosT,
                            const float* __restrict__ scaleT) {
    int chunk = blockIdx.x * 256 + threadIdx.x;
    int which = blockIdx.y;
    int row = chunk >> 9;
    int c = (chunk & 511) << 2;
    int s = row & (S_ - 1);
    int j = (c & 127) >> 1;
    float* ptr = which ? K : Q;
    float4 x = *(float4*)&ptr[(size_t)row * ROWLEN + c];
    int tb = s * 64 + j;
    float sc0 = scaleT[tb], sc1 = scaleT[tb + 1];
    if (which) { sc0 = 1.0f / sc0; sc1 = 1.0f / sc1; }
    float c0 = cosT[tb] * sc0,     s0 = sinT[tb] * sc0;
    float c1 = cosT[tb + 1] * sc1, s1 = sinT[tb + 1] * sc1;
    float4 y;
    y.x = x.x * c0 - x.y * s0;
    y.y = x.y * c0 + x.x * s0;
    y.z = x.z * c1 - x.w * s1;
    y.w = x.w * c1 + x.z * s1;
    *(float4*)&ptr[(size_t)row * ROWLEN + c] = y;
}

// ---------------------------------------------------------------------------
// Retention (fp32). Block: 256 threads; grid (16, 32).
// Each block runs s-tiles {bx, 31-bx} (load-balanced, 33 t-iters total).
// Conflict-free LDS: t-cols stride 8 per thread, Y-cols stride 32.
// ---------------------------------------------------------------------------
__global__ __launch_bounds__(256) void retention_kernel(
    const float* __restrict__ Q, const float* __restrict__ K,
    const float* __restrict__ V, float* __restrict__ Y) {
    __shared__ float Qs[32][132];
    __shared__ float Ks[32][132];
    __shared__ float Vs[32][132];
    __shared__ float Ss[32][33];

    int bn = blockIdx.y;
    int b = bn >> 4, n = bn & 15;
    int tid = threadIdx.x;

    const float l0 = -3.4657359027997265f;  // ln(1/32)
    const float l1 = -6.2383246250395077f;  // ln(1/512)
    float gamma = 1.0f - expf(l0 + (l1 - l0) * (float)n * (1.0f / 15.0f));
    float log2g = log2f(gamma);

    int r    = tid >> 3;
    int tcol = tid & 7;            // S cols {tcol + 8q}
    int c0   = (tid & 7) * 4;      // Y cols {c0 + 32*c4}

    for (int pass = 0; pass < 2; ++pass) {
        int sTile = (pass == 0) ? blockIdx.x : 31 - blockIdx.x;
        int s0 = sTile * 32;

        __syncthreads();
        const float* Qbase = Q + (size_t)(b * S_ + s0) * ROWLEN + n * 128;
        for (int it = 0; it < 4; ++it) {
            int f4 = it * 256 + tid;
            int rr = f4 >> 5, c4 = (f4 & 31) * 4;
            *(float4*)&Qs[rr][c4] = *(const float4*)&Qbase[(size_t)rr * ROWLEN + c4];
        }

        float yacc[16];
#pragma unroll
        for (int i = 0; i < 16; ++i) yacc[i] = 0.0f;

        for (int t0 = 0; t0 <= s0; t0 += 32) {
            __syncthreads();
            const float* Kbase = K + (size_t)(b * S_ + t0) * ROWLEN + n * 128;
            const float* Vbase = V + (size_t)(b * S_ + t0) * ROWLEN + n * 128;
            for (int it = 0; it < 4; ++it) {
                int f4 = it * 256 + tid;
                int rr = f4 >> 5, c4 = (f4 & 31) * 4;
                *(float4*)&Ks[rr][c4] = *(const float4*)&Kbase[(size_t)rr * ROWLEN + c4];
                *(float4*)&Vs[rr][c4] = *(const float4*)&Vbase[(size_t)rr * ROWLEN + c4];
            }
            __syncthreads();

            float acc[4] = {0.0f, 0.0f, 0.0f, 0.0f};
#pragma unroll 8
            for (int k4 = 0; k4 < 32; ++k4) {
                float4 qv = *(const float4*)&Qs[r][k4 * 4];
#pragma unroll
                for (int q = 0; q < 4; ++q) {
                    float4 kv = *(const float4*)&Ks[tcol + 8 * q][k4 * 4];
                    acc[q] += qv.x * kv.x + qv.y * kv.y + qv.z * kv.z + qv.w * kv.w;
                }
            }
#pragma unroll
            for (int q = 0; q < 4; ++q) {
                int dt = (s0 + r) - (t0 + tcol + 8 * q);
                float wgt = (dt < 0) ? 0.0f : exp2f((float)dt * log2g);
                Ss[r][tcol + 8 * q] = acc[q] * wgt;
            }
            __syncthreads();

#pragma unroll 8
            for (int t = 0; t < 32; ++t) {
                float wgt = Ss[r][t];
#pragma unroll
                for (int c4 = 0; c4 < 4; ++c4) {
                    float4 vv = *(const float4*)&Vs[t][c0 + 32 * c4];
                    yacc[c4 * 4 + 0] += wgt * vv.x;
                    yacc[c4 * 4 + 1] += wgt * vv.y;
                    yacc[c4 * 4 + 2] += wgt * vv.z;
                    yacc[c4 * 4 + 3] += wgt * vv.w;
                }
            }
        }

        float* Ybase = Y + (size_t)(b * S_ + s0) * ROWLEN + n * 128;
#pragma unroll
        for (int c4 = 0; c4 < 4; ++c4) {
            float4 v = make_float4(yacc[c4 * 4 + 0], yacc[c4 * 4 + 1],
                                   yacc[c4 * 4 + 2], yacc[c4 * 4 + 3]);
            *(float4*)&Ybase[(size_t)r * ROWLEN + c0 + 32 * c4] = v;
        }
    }
}

// ---------------------------------------------------------------------------
// GroupNorm(16x128) + SiLU gate; outputs split-bf16 Z (A operand of out GEMM)
// ---------------------------------------------------------------------------
__global__ __launch_bounds__(256) void gn_gate_kernel(
    const float* __restrict__ Y, const float* __restrict__ G,
    const float* __restrict__ gnw, const float* __restrict__ gnb,
    short* __restrict__ Zhi, short* __restrict__ Zlo) {
    int row = blockIdx.x;
    int lane = threadIdx.x & 63;
    int wave = threadIdx.x >> 6;
    const float* yrow = Y + (size_t)row * ROWLEN;
    const float* grow = G + (size_t)row * ROWLEN;
    size_t zoff = (size_t)row * ROWLEN;

    for (int g = wave * 4; g < wave * 4 + 4; ++g) {
        float y0 = yrow[g * 128 + lane];
        float y1 = yrow[g * 128 + 64 + lane];
        float sum = y0 + y1;
#pragma unroll
        for (int m = 32; m >= 1; m >>= 1) sum += __shfl_xor(sum, m, 64);
        float mean = sum * (1.0f / 128.0f);
        float d0 = y0 - mean, d1 = y1 - mean;
        float vs = d0 * d0 + d1 * d1;
#pragma unroll
        for (int m = 32; m >= 1; m >>= 1) vs += __shfl_xor(vs, m, 64);
        float rinv = rsqrtf(vs * (1.0f / 128.0f) + 1e-5f);
        int h0 = g * 128 + lane, h1 = h0 + 64;
        float yn0 = d0 * rinv * gnw[h0] + gnb[h0];
        float yn1 = d1 * rinv * gnw[h1] + gnb[h1];
        float gv0 = grow[h0], gv1 = grow[h1];
        float z0 = (gv0 / (1.0f + expf(-gv0))) * yn0;
        float z1 = (gv1 / (1.0f + expf(-gv1))) * yn1;
        short h, l;
        f2hilo(z0, h, l); Zhi[zoff + h0] = h; Zlo[zoff + h0] = l;
        f2hilo(z1, h, l); Zhi[zoff + h1] = h; Zlo[zoff + h1] = l;
    }
}

// ---------------------------------------------------------------------------
extern "C" void kernel_launch(void* const* d_in, const int* in_sizes, int n_in,
                              void* d_out, int out_size, void* d_ws, size_t ws_size,
                              hipStream_t stream) {
    const float* X   = (const float*)d_in[0];
    const float* W_Q = (const float*)d_in[1];
    const float* W_K = (const float*)d_in[2];
    const float* W_V = (const float*)d_in[3];
    const float* W_G = (const float*)d_in[4];
    const float* W_O = (const float*)d_in[5];
    const float* gnw = (const float*)d_in[6];
    const float* gnb = (const float*)d_in[7];
    float* out = (float*)d_out;
    float* ws  = (float*)d_ws;

    float* Qb = ws;
    float* Kb = Qb + MATF;
    float* Vb = Kb + MATF;
    float* Gb = Vb + MATF;
    float* Yb = Gb + MATF;
    short* Xhi  = (short*)(Yb + MATF);
    short* Xlo  = Xhi + MATF;
    short* Wthi = Xlo + MATF;
    short* Wtlo = Wthi + MATF;
    float* sinT   = (float*)(Wtlo + MATF);
    float* cosT   = sinT + S_ * 64;
    float* scaleT = cosT + S_ * 64;
    short* Zhi = Xhi;   // X dead after gate GEMM
    short* Zlo = Xlo;

    tables_kernel<<<256, 256, 0, stream>>>(sinT, cosT, scaleT);
    cvt_hilo_kernel<<<4096, 256, 0, stream>>>(X, Xhi, Xlo);

    dim3 gw(64, 64), gg(16, 16);
    cvtWt_kernel<<<gw, 256, 0, stream>>>(W_Q, Wthi, Wtlo, 1);
    mfma_gemm_kernel<<<gg, 256, 0, stream>>>(Xhi, Xlo, Wthi, Wtlo, Qb);
    cvtWt_kernel<<<gw, 256, 0, stream>>>(W_K, Wthi, Wtlo, 1);
    mfma_gemm_kernel<<<gg, 256, 0, stream>>>(Xhi, Xlo, Wthi, Wtlo, Kb);
    cvtWt_kernel<<<gw, 256, 0, stream>>>(W_V, Wthi, Wtlo, 1);
    mfma_gemm_kernel<<<gg, 256, 0, stream>>>(Xhi, Xlo, Wthi, Wtlo, Vb);
    cvtWt_kernel<<<gw, 256, 0, stream>>>(W_G, Wthi, Wtlo, 0);
    mfma_gemm_kernel<<<gg, 256, 0, stream>>>(Xhi, Xlo, Wthi, Wtlo, Gb);

    xpos_kernel<<<dim3(4096, 2), 256, 0, stream>>>(Qb, Kb, sinT, cosT, scaleT);

    retention_kernel<<<dim3(16, 32), 256, 0, stream>>>(Qb, Kb, Vb, Yb);

    gn_gate_kernel<<<BS_, 256, 0, stream>>>(Yb, Gb, gnw, gnb, Zhi, Zlo);

    cvtWt_kernel<<<gw, 256, 0, stream>>>(W_O, Wthi, Wtlo, 0);
    mfma_gemm_kernel<<<gg, 256, 0, stream>>>(Zhi, Zlo, Wthi, Wtlo, out);
}

// Round 3
// 723.992 us; speedup vs baseline: 2.9107x; 1.5442x over previous
//
#include <hip/hip_runtime.h>
#include <math.h>

// Shapes (fixed): B=2, S=1024, H=2048, nheads=16, d=128
#define S_     1024
#define H_     2048
#define BS_    2048
#define MATF   ((size_t)BS_ * H_)    // 4,194,304 elements (2048x2048)

typedef __bf16 bf16x8 __attribute__((ext_vector_type(8)));
typedef float  f32x4  __attribute__((ext_vector_type(4)));

__device__ __forceinline__ void f2hilo(float x, short& h, short& l) {
    __bf16 bh = (__bf16)x;
    float  r  = x - (float)bh;
    __bf16 bl = (__bf16)r;
    h = __builtin_bit_cast(short, bh);
    l = __builtin_bit_cast(short, bl);
}

__device__ __forceinline__ void gload16(const void* g, void* l) {
    __builtin_amdgcn_global_load_lds(
        (const __attribute__((address_space(1))) void*)g,
        (__attribute__((address_space(3))) void*)l, 16, 0, 0);
}

// ---------------------------------------------------------------------------
// xPos tables: sin/cos/scale, each [S][64]
// ---------------------------------------------------------------------------
__global__ void tables_kernel(float* __restrict__ sinT, float* __restrict__ cosT,
                              float* __restrict__ scaleT) {
    int idx = blockIdx.x * 256 + threadIdx.x;   // 0 .. 65535
    int s = idx >> 6, j = idx & 63;
    float xscale   = (2.0f * j + 0.4f * 128.0f) / (1.4f * 128.0f);
    float sc       = powf(xscale, (float)s * (1.0f / 512.0f));
    float inv_freq = powf(10000.0f, -(float)j * (1.0f / 64.0f));
    float ang      = (float)s * inv_freq;
    sinT[idx]   = sinf(ang);
    cosT[idx]   = cosf(ang);
    scaleT[idx] = sc;
}

// ---------------------------------------------------------------------------
// fp32 -> bf16 hi/lo split, elementwise
// ---------------------------------------------------------------------------
__global__ __launch_bounds__(256) void cvt_hilo_kernel(
    const float* __restrict__ src, short* __restrict__ hi, short* __restrict__ lo) {
    int i = blockIdx.x * 256 + threadIdx.x;
    float4 v = *(const float4*)&src[(size_t)i * 4];
    short h[4], l[4];
    f2hilo(v.x, h[0], l[0]);
    f2hilo(v.y, h[1], l[1]);
    f2hilo(v.z, h[2], l[2]);
    f2hilo(v.w, h[3], l[3]);
    *(short4*)&hi[(size_t)i * 4] = make_short4(h[0], h[1], h[2], h[3]);
    *(short4*)&lo[(size_t)i * 4] = make_short4(l[0], l[1], l[2], l[3]);
}

// ---------------------------------------------------------------------------
// fp32 -> plain bf16
// ---------------------------------------------------------------------------
__global__ __launch_bounds__(256) void cvt_bf16_kernel(
    const float* __restrict__ src, short* __restrict__ dst) {
    int i = blockIdx.x * 256 + threadIdx.x;
    float4 v = *(const float4*)&src[(size_t)i * 4];
    short4 o;
    o.x = __builtin_bit_cast(short, (__bf16)v.x);
    o.y = __builtin_bit_cast(short, (__bf16)v.y);
    o.z = __builtin_bit_cast(short, (__bf16)v.z);
    o.w = __builtin_bit_cast(short, (__bf16)v.w);
    *(short4*)&dst[(size_t)i * 4] = o;
}

// ---------------------------------------------------------------------------
// Weight -> transposed bf16 hi/lo: Wt[n][k] = W[k][n]
// headed=1: W is (16, 2048, 128); headed=0: (2048,2048) row-major
// ---------------------------------------------------------------------------
__global__ __launch_bounds__(256) void cvtWt_kernel(
    const float* __restrict__ W, short* __restrict__ hi, short* __restrict__ lo,
    int headed) {
    __shared__ float T[32][33];
    int k0 = blockIdx.x * 32, n0 = blockIdx.y * 32;
    int tx = threadIdx.x & 7, ty = threadIdx.x >> 3;
    const float* src;
    if (headed) {
        int head = n0 >> 7, d0 = n0 & 127;
        src = W + ((size_t)head * 2048 + (k0 + ty)) * 128 + d0 + tx * 4;
    } else {
        src = W + (size_t)(k0 + ty) * 2048 + n0 + tx * 4;
    }
    float4 v = *(const float4*)src;
    T[ty][tx * 4 + 0] = v.x;
    T[ty][tx * 4 + 1] = v.y;
    T[ty][tx * 4 + 2] = v.z;
    T[ty][tx * 4 + 3] = v.w;
    __syncthreads();
    int nl = ty, k4 = tx * 4;
    short h[4], l[4];
#pragma unroll
    for (int j = 0; j < 4; ++j) f2hilo(T[k4 + j][nl], h[j], l[j]);
    size_t off = (size_t)(n0 + nl) * 2048 + k0 + k4;
    *(short4*)&hi[off] = make_short4(h[0], h[1], h[2], h[3]);
    *(short4*)&lo[off] = make_short4(l[0], l[1], l[2], l[3]);
}

// ---------------------------------------------------------------------------
// Split-bf16 MFMA GEMM: C[M][N](ldC) = (Ahi+Alo)[M][2048] * Bt[N][2048]^T
// 128x128 tile, BK=32, 256 thr (4 waves 2x2). grid = (N/128, M/128).
// ---------------------------------------------------------------------------
__global__ __launch_bounds__(256) void mfma_gemm_kernel(
    const short* __restrict__ Ahi, const short* __restrict__ Alo,
    const short* __restrict__ Bhi, const short* __restrict__ Blo,
    float* __restrict__ C, int ldC) {
    __shared__ short lds[4 * 4096];

    int tid = threadIdx.x;
    int w = tid >> 6, l = tid & 63;

    int ntx = gridDim.x;
    int nwg = gridDim.x * gridDim.y;
    int bid = blockIdx.y * ntx + blockIdx.x;
    int swz = (bid & 7) * (nwg >> 3) + (bid >> 3);   // nwg % 8 == 0
    int row0 = (swz / ntx) * 128, col0 = (swz % ntx) * 128;

    int wr = w >> 1, wc = w & 1;

    f32x4 acc[4][4] = {};

    int e0 = tid, e1 = 256 + tid;
    int kb0 = e0 >> 7, rr0 = e0 & 127;
    int kb1 = e1 >> 7, rr1 = e1 & 127;
    const short* pa0h = Ahi + (size_t)(row0 + rr0) * 2048 + kb0 * 8;
    const short* pa1h = Ahi + (size_t)(row0 + rr1) * 2048 + kb1 * 8;
    const short* pa0l = Alo + (size_t)(row0 + rr0) * 2048 + kb0 * 8;
    const short* pa1l = Alo + (size_t)(row0 + rr1) * 2048 + kb1 * 8;
    const short* pb0h = Bhi + (size_t)(col0 + rr0) * 2048 + kb0 * 8;
    const short* pb1h = Bhi + (size_t)(col0 + rr1) * 2048 + kb1 * 8;
    const short* pb0l = Blo + (size_t)(col0 + rr0) * 2048 + kb0 * 8;
    const short* pb1l = Blo + (size_t)(col0 + rr1) * 2048 + kb1 * 8;
    short* lA0  = &lds[0 * 4096 + w * 512];
    short* lA1  = &lds[0 * 4096 + (4 + w) * 512];
    short* lAl0 = &lds[1 * 4096 + w * 512];
    short* lAl1 = &lds[1 * 4096 + (4 + w) * 512];
    short* lB0  = &lds[2 * 4096 + w * 512];
    short* lB1  = &lds[2 * 4096 + (4 + w) * 512];
    short* lBl0 = &lds[3 * 4096 + w * 512];
    short* lBl1 = &lds[3 * 4096 + (4 + w) * 512];

    int lr = l & 15, lk = l >> 4;
    int abase = (lk << 10) + (wr << 9) + (lr << 3);
    int bbase = (lk << 10) + (wc << 9) + (lr << 3);

    for (int k0 = 0; k0 < 2048; k0 += 32) {
        gload16(pa0h + k0, lA0);
        gload16(pa1h + k0, lA1);
        gload16(pa0l + k0, lAl0);
        gload16(pa1l + k0, lAl1);
        gload16(pb0h + k0, lB0);
        gload16(pb1h + k0, lB1);
        gload16(pb0l + k0, lBl0);
        gload16(pb1l + k0, lBl1);
        __syncthreads();

        bf16x8 ah[4], al[4], bh[4], bl[4];
#pragma unroll
        for (int m = 0; m < 4; ++m) {
            ah[m] = *(const bf16x8*)&lds[0 * 4096 + abase + m * 128];
            al[m] = *(const bf16x8*)&lds[1 * 4096 + abase + m * 128];
        }
#pragma unroll
        for (int n = 0; n < 4; ++n) {
            bh[n] = *(const bf16x8*)&lds[2 * 4096 + bbase + n * 128];
            bl[n] = *(const bf16x8*)&lds[3 * 4096 + bbase + n * 128];
        }
#pragma unroll
        for (int m = 0; m < 4; ++m)
#pragma unroll
            for (int n = 0; n < 4; ++n) {
                acc[m][n] = __builtin_amdgcn_mfma_f32_16x16x32_bf16(ah[m], bh[n], acc[m][n], 0, 0, 0);
                acc[m][n] = __builtin_amdgcn_mfma_f32_16x16x32_bf16(ah[m], bl[n], acc[m][n], 0, 0, 0);
                acc[m][n] = __builtin_amdgcn_mfma_f32_16x16x32_bf16(al[m], bh[n], acc[m][n], 0, 0, 0);
            }
        __syncthreads();
    }

#pragma unroll
    for (int m = 0; m < 4; ++m)
#pragma unroll
        for (int n = 0; n < 4; ++n) {
            int row = row0 + (wr << 6) + (m << 4) + (lk << 2);
            int col = col0 + (wc << 6) + (n << 4) + lr;
            float* cp = &C[(size_t)row * ldC + col];
            cp[0 * (size_t)ldC] = acc[m][n][0];
            cp[1 * (size_t)ldC] = acc[m][n][1];
            cp[2 * (size_t)ldC] = acc[m][n][2];
            cp[3 * (size_t)ldC] = acc[m][n][3];
        }
}

// ---------------------------------------------------------------------------
// xPos rotary: read Q,K fp32 from QKG (ld 6144), write split-bf16 Q,K
// ---------------------------------------------------------------------------
__global__ void xpos_kernel(const float* __restrict__ QKG,
                            short* __restrict__ Qhi, short* __restrict__ Qlo,
                            short* __restrict__ Khi, short* __restrict__ Klo,
                            const float* __restrict__ sinT,
                            const float* __restrict__ cosT,
                            const float* __restrict__ scaleT) {
    int chunk = blockIdx.x * 256 + threadIdx.x;
    int which = blockIdx.y;                        // 0=Q, 1=K
    int row = chunk >> 9;
    int c = (chunk & 511) << 2;
    int s = row & (S_ - 1);
    int j = (c & 127) >> 1;
    float4 x = *(const float4*)&QKG[(size_t)row * 6144 + which * 2048 + c];
    int tb = s * 64 + j;
    float sc0 = scaleT[tb], sc1 = scaleT[tb + 1];
    if (which) { sc0 = 1.0f / sc0; sc1 = 1.0f / sc1; }
    float c0 = cosT[tb] * sc0,     s0 = sinT[tb] * sc0;
    float c1 = cosT[tb + 1] * sc1, s1 = sinT[tb + 1] * sc1;
    float4 y;
    y.x = x.x * c0 - x.y * s0;
    y.y = x.y * c0 + x.x * s0;
    y.z = x.z * c1 - x.w * s1;
    y.w = x.w * c1 + x.z * s1;
    short* hi = which ? Khi : Qhi;
    short* lo = which ? Klo : Qlo;
    short h[4], l[4];
    f2hilo(y.x, h[0], l[0]);
    f2hilo(y.y, h[1], l[1]);
    f2hilo(y.z, h[2], l[2]);
    f2hilo(y.w, h[3], l[3]);
    *(short4*)&hi[(size_t)row * 2048 + c] = make_short4(h[0], h[1], h[2], h[3]);
    *(short4*)&lo[(size_t)row * 2048 + c] = make_short4(l[0], l[1], l[2], l[3]);
}

// ---------------------------------------------------------------------------
// MFMA retention. Block = 512 thr (8 waves), s-tile 64, t-tile 64.
// Grid (8 pairs, 32 bn): block does s-tiles {bx, 15-bx} (17 t-tiles total).
// QK^T: 3-term split-bf16; decay in-register; S,V plain bf16 for PV.
// PV computed transposed (Y^T = Vt*S^T) so Vt [v][t] is the A operand.
// ---------------------------------------------------------------------------
__global__ __launch_bounds__(512) void retention_mfma_kernel(
    const short* __restrict__ Qhi, const short* __restrict__ Qlo,
    const short* __restrict__ Khi, const short* __restrict__ Klo,
    const short* __restrict__ Vtb, float* __restrict__ Y /* ld 6144 */) {
    __shared__ short KldsH[8192];   // [kblk 16][t 64][8]  (t XOR-swizzled)
    __shared__ short KldsL[8192];
    __shared__ short Vlds[8192];    // [tblk 8][v 128][8]  (v XOR-swizzled)
    __shared__ short Slds[8 * 544]; // [tblk 8][s 64][8], padded stride 544

    int tid = threadIdx.x;
    int w = tid >> 6, lane = tid & 63;
    int lr = lane & 15, lk = lane >> 4;
    int bn = blockIdx.y;
    int b = bn >> 4, n = bn & 15;

    const float l0 = -3.4657359027997265f;  // ln(1/32)
    const float l1 = -6.2383246250395077f;  // ln(1/512)
    float gamma = 1.0f - expf(l0 + (l1 - l0) * (float)n * (1.0f / 15.0f));
    float log2g = log2f(gamma);

    int sh = (w & 1) * 32;     // s-half owned (QK rows / PV cols)
    int tq = (w >> 1) * 16;    // t 16-block owned in QK
    int vq = (w >> 1) * 32;    // v 32-block owned in PV

    for (int pass = 0; pass < 2; ++pass) {
        int sTile = pass ? (15 - (int)blockIdx.x) : (int)blockIdx.x;
        int s0 = sTile * 64;

        // Q fragments (A-layout) straight from global
        bf16x8 qh[2][4], ql[2][4];
#pragma unroll
        for (int m = 0; m < 2; ++m)
#pragma unroll
            for (int ks = 0; ks < 4; ++ks) {
                size_t off = (size_t)(b * S_ + s0 + sh + m * 16 + lr) * 2048
                           + n * 128 + ks * 32 + lk * 8;
                qh[m][ks] = *(const bf16x8*)&Qhi[off];
                ql[m][ks] = *(const bf16x8*)&Qlo[off];
            }

        f32x4 yacc[2][2] = {};

        for (int t0 = 0; t0 <= s0; t0 += 64) {
            // ---- stage K (hi/lo) and Vt (pre-swizzled global source, linear LDS dest)
#pragma unroll
            for (int i = 0; i < 2; ++i) {
                int e = i * 512 + tid;
                int kb = e >> 6, traw = e & 63;
                int t = traw ^ ((kb & 3) << 1);
                size_t koff = (size_t)(b * S_ + t0 + t) * 2048 + n * 128 + kb * 8;
                short* dst = &KldsH[(i * 512 + w * 64) * 8];
                gload16(Khi + koff, dst);
                short* dstl = &KldsL[(i * 512 + w * 64) * 8];
                gload16(Klo + koff, dstl);
                int tb = e >> 7, vraw = e & 127;
                int v = vraw ^ ((tb & 3) << 1);
                size_t voff = (size_t)(n * 128 + v) * 2048 + b * S_ + t0 + tb * 8;
                short* dstv = &Vlds[(i * 512 + w * 64) * 8];
                gload16(Vtb + voff, dstv);
            }
            __syncthreads();

            // ---- QK^T (split x3) for this wave's [32 s][16 t]
            f32x4 sacc[2] = {};
#pragma unroll
            for (int ks = 0; ks < 4; ++ks) {
                int kb = ks * 4 + lk;
                int entry = kb * 64 + ((tq + lr) ^ ((kb & 3) << 1));
                bf16x8 kh = *(const bf16x8*)&KldsH[entry * 8];
                bf16x8 kl = *(const bf16x8*)&KldsL[entry * 8];
#pragma unroll
                for (int m = 0; m < 2; ++m) {
                    sacc[m] = __builtin_amdgcn_mfma_f32_16x16x32_bf16(qh[m][ks], kh, sacc[m], 0, 0, 0);
                    sacc[m] = __builtin_amdgcn_mfma_f32_16x16x32_bf16(qh[m][ks], kl, sacc[m], 0, 0, 0);
                    sacc[m] = __builtin_amdgcn_mfma_f32_16x16x32_bf16(ql[m][ks], kh, sacc[m], 0, 0, 0);
                }
            }

            // ---- decay + mask + bf16, write S to LDS ([tblk][s][8], stride 544)
            int t_loc = tq + lr;
            bool diag = (t0 == s0);
#pragma unroll
            for (int m = 0; m < 2; ++m)
#pragma unroll
                for (int i = 0; i < 4; ++i) {
                    int s_loc = sh + m * 16 + lk * 4 + i;
                    int dt = (s0 + s_loc) - (t0 + t_loc);
                    float wgt = exp2f((float)dt * log2g);
                    if (diag && dt < 0) wgt = 0.0f;
                    float val = sacc[m][i] * wgt;
                    Slds[(t_loc >> 3) * 544 + s_loc * 8 + (t_loc & 7)] =
                        __builtin_bit_cast(short, (__bf16)val);
                }
            __syncthreads();

            // ---- PV (transposed): yacc[v][s] += Vt-frag x S-frag
#pragma unroll
            for (int kt = 0; kt < 2; ++kt) {
                int kb = kt * 4 + lk;
                bf16x8 vf[2], sf[2];
#pragma unroll
                for (int m2 = 0; m2 < 2; ++m2) {
                    int v = vq + m2 * 16 + lr;
                    vf[m2] = *(const bf16x8*)&Vlds[(kb * 128 + (v ^ ((kb & 3) << 1))) * 8];
                }
#pragma unroll
                for (int n2 = 0; n2 < 2; ++n2) {
                    int scol = sh + n2 * 16 + lr;
                    sf[n2] = *(const bf16x8*)&Slds[kb * 544 + scol * 8];
                }
#pragma unroll
                for (int m2 = 0; m2 < 2; ++m2)
#pragma unroll
                    for (int n2 = 0; n2 < 2; ++n2)
                        yacc[m2][n2] = __builtin_amdgcn_mfma_f32_16x16x32_bf16(
                            vf[m2], sf[n2], yacc[m2][n2], 0, 0, 0);
            }
            __syncthreads();
        }

        // ---- store Y: D[v][s]: col s = lr, rows v = lk*4+i (4 consecutive -> float4)
#pragma unroll
        for (int m2 = 0; m2 < 2; ++m2)
#pragma unroll
            for (int n2 = 0; n2 < 2; ++n2) {
                int srow = b * S_ + s0 + sh + n2 * 16 + lr;
                int vcol = n * 128 + vq + m2 * 16 + lk * 4;
                f32x4 v = yacc[m2][n2];
                *(float4*)&Y[(size_t)srow * 6144 + vcol] =
                    make_float4(v[0], v[1], v[2], v[3]);
            }
    }
}

// ---------------------------------------------------------------------------
// GroupNorm(16x128) + SiLU gate -> split-bf16 Z
// ---------------------------------------------------------------------------
__global__ __launch_bounds__(256) void gn_gate_kernel(
    const float* __restrict__ Y, const float* __restrict__ G,
    const float* __restrict__ gnw, const float* __restrict__ gnb,
    short* __restrict__ Zhi, short* __restrict__ Zlo) {
    int row = blockIdx.x;
    int lane = threadIdx.x & 63;
    int wave = threadIdx.x >> 6;
    const float* yrow = Y + (size_t)row * 6144;
    const float* grow = G + (size_t)row * 6144;
    size_t zoff = (size_t)row * 2048;

    for (int g = wave * 4; g < wave * 4 + 4; ++g) {
        float y0 = yrow[g * 128 + lane];
        float y1 = yrow[g * 128 + 64 + lane];
        float sum = y0 + y1;
#pragma unroll
        for (int m = 32; m >= 1; m >>= 1) sum += __shfl_xor(sum, m, 64);
        float mean = sum * (1.0f / 128.0f);
        float d0 = y0 - mean, d1 = y1 - mean;
        float vs = d0 * d0 + d1 * d1;
#pragma unroll
        for (int m = 32; m >= 1; m >>= 1) vs += __shfl_xor(vs, m, 64);
        float rinv = rsqrtf(vs * (1.0f / 128.0f) + 1e-5f);
        int h0 = g * 128 + lane, h1 = h0 + 64;
        float yn0 = d0 * rinv * gnw[h0] + gnb[h0];
        float yn1 = d1 * rinv * gnw[h1] + gnb[h1];
        float gv0 = grow[h0], gv1 = grow[h1];
        float z0 = (gv0 / (1.0f + expf(-gv0))) * yn0;
        float z1 = (gv1 / (1.0f + expf(-gv1))) * yn1;
        short h, l;
        f2hilo(z0, h, l); Zhi[zoff + h0] = h; Zlo[zoff + h0] = l;
        f2hilo(z1, h, l); Zhi[zoff + h1] = h; Zlo[zoff + h1] = l;
    }
}

// ---------------------------------------------------------------------------
extern "C" void kernel_launch(void* const* d_in, const int* in_sizes, int n_in,
                              void* d_out, int out_size, void* d_ws, size_t ws_size,
                              hipStream_t stream) {
    const float* X   = (const float*)d_in[0];
    const float* W_Q = (const float*)d_in[1];
    const float* W_K = (const float*)d_in[2];
    const float* W_V = (const float*)d_in[3];
    const float* W_G = (const float*)d_in[4];
    const float* W_O = (const float*)d_in[5];
    const float* gnw = (const float*)d_in[6];
    const float* gnb = (const float*)d_in[7];
    float* out = (float*)d_out;
    float* ws  = (float*)d_ws;

    // Workspace map (units of MATF floats):
    // [0,1): Xhi+Xlo  [1,5): Wt hi/lo (8192x2048 each)  [5,8): QKG fp32 (ld 6144)
    // [8,10): Qhi/Qlo/Khi/Klo  [10,10.5): Vtb  [10.5,+): tables
    short* Xhi  = (short*)ws;
    short* Xlo  = Xhi + MATF;
    short* Wthi = (short*)(ws + MATF);
    short* Wtlo = Wthi + 4 * MATF;
    float* QKG  = ws + 5 * MATF;          // Q cols 0..2047, K 2048..4095, G 4096..6143
    short* Qhi  = (short*)(ws + 8 * MATF);
    short* Qlo  = Qhi + MATF;
    short* Khi  = Qlo + MATF;
    short* Klo  = Khi + MATF;
    short* Vtb  = (short*)(ws + 10 * MATF);
    float* sinT   = ws + 10 * MATF + MATF / 2;
    float* cosT   = sinT + S_ * 64;
    float* scaleT = cosT + S_ * 64;
    float* Vt32 = (float*)Wthi;           // reuse Wt QKG-slots after QKG gemm
    short* Zhi = Xhi;                     // X dead after Vt gemm
    short* Zlo = Xlo;

    tables_kernel<<<256, 256, 0, stream>>>(sinT, cosT, scaleT);
    cvt_hilo_kernel<<<4096, 256, 0, stream>>>(X, Xhi, Xlo);

    dim3 gw(64, 64);
    cvtWt_kernel<<<gw, 256, 0, stream>>>(W_Q, Wthi,               Wtlo,               1);
    cvtWt_kernel<<<gw, 256, 0, stream>>>(W_K, Wthi + 2048 * 2048, Wtlo + 2048 * 2048, 1);
    cvtWt_kernel<<<gw, 256, 0, stream>>>(W_G, Wthi + (size_t)4096 * 2048, Wtlo + (size_t)4096 * 2048, 0);
    cvtWt_kernel<<<gw, 256, 0, stream>>>(W_V, Wthi + (size_t)6144 * 2048, Wtlo + (size_t)6144 * 2048, 1);

    // Fused Q/K/G projection: C = X * [WQ|WK|WG]^T-layout, 768 wgs
    mfma_gemm_kernel<<<dim3(48, 16), 256, 0, stream>>>(Xhi, Xlo, Wthi, Wtlo, QKG, 6144);

    // V^T directly: Vt[v][bs] = WtV[v][k] . X[bs][k]
    mfma_gemm_kernel<<<dim3(16, 16), 256, 0, stream>>>(
        Wthi + (size_t)6144 * 2048, Wtlo + (size_t)6144 * 2048, Xhi, Xlo, Vt32, 2048);
    cvt_bf16_kernel<<<4096, 256, 0, stream>>>(Vt32, Vtb);

    xpos_kernel<<<dim3(4096, 2), 256, 0, stream>>>(QKG, Qhi, Qlo, Khi, Klo, sinT, cosT, scaleT);

    // Retention: Y into QKG cols 0..2047 (Q fp32 dead after xpos)
    retention_mfma_kernel<<<dim3(8, 32), 512, 0, stream>>>(Qhi, Qlo, Khi, Klo, Vtb, QKG);

    gn_gate_kernel<<<BS_, 256, 0, stream>>>(QKG, QKG + 4096, gnw, gnb, Zhi, Zlo);

    cvtWt_kernel<<<gw, 256, 0, stream>>>(W_O, Wthi, Wtlo, 0);
    mfma_gemm_kernel<<<dim3(16, 16), 256, 0, stream>>>(Zhi, Zlo, Wthi, Wtlo, out, 2048);
}

// Round 4
// 642.644 us; speedup vs baseline: 3.2792x; 1.1266x over previous
//
#include <hip/hip_runtime.h>
#include <math.h>

// Shapes (fixed): B=2, S=1024, H=2048, nheads=16, d=128
#define S_     1024
#define H_     2048
#define BS_    2048
#define MATF   ((size_t)BS_ * H_)    // 4,194,304 elements (2048x2048)

typedef __bf16 bf16x8 __attribute__((ext_vector_type(8)));
typedef float  f32x4  __attribute__((ext_vector_type(4)));

__device__ __forceinline__ void f2hilo(float x, short& h, short& l) {
    __bf16 bh = (__bf16)x;
    float  r  = x - (float)bh;
    __bf16 bl = (__bf16)r;
    h = __builtin_bit_cast(short, bh);
    l = __builtin_bit_cast(short, bl);
}

__device__ __forceinline__ void gload16(const void* g, void* l) {
    __builtin_amdgcn_global_load_lds(
        (const __attribute__((address_space(1))) void*)g,
        (__attribute__((address_space(3))) void*)l, 16, 0, 0);
}

// ---------------------------------------------------------------------------
// xPos tables: sin/cos/scale, each [S][64]
// ---------------------------------------------------------------------------
__global__ void tables_kernel(float* __restrict__ sinT, float* __restrict__ cosT,
                              float* __restrict__ scaleT) {
    int idx = blockIdx.x * 256 + threadIdx.x;
    int s = idx >> 6, j = idx & 63;
    float xscale   = (2.0f * j + 0.4f * 128.0f) / (1.4f * 128.0f);
    float sc       = powf(xscale, (float)s * (1.0f / 512.0f));
    float inv_freq = powf(10000.0f, -(float)j * (1.0f / 64.0f));
    float ang      = (float)s * inv_freq;
    sinT[idx]   = sinf(ang);
    cosT[idx]   = cosf(ang);
    scaleT[idx] = sc;
}

// ---------------------------------------------------------------------------
// fp32 -> bf16 hi/lo split, elementwise
// ---------------------------------------------------------------------------
__global__ __launch_bounds__(256) void cvt_hilo_kernel(
    const float* __restrict__ src, short* __restrict__ hi, short* __restrict__ lo) {
    int i = blockIdx.x * 256 + threadIdx.x;
    float4 v = *(const float4*)&src[(size_t)i * 4];
    short h[4], l[4];
    f2hilo(v.x, h[0], l[0]);
    f2hilo(v.y, h[1], l[1]);
    f2hilo(v.z, h[2], l[2]);
    f2hilo(v.w, h[3], l[3]);
    *(short4*)&hi[(size_t)i * 4] = make_short4(h[0], h[1], h[2], h[3]);
    *(short4*)&lo[(size_t)i * 4] = make_short4(l[0], l[1], l[2], l[3]);
}

// ---------------------------------------------------------------------------
// All 4 projection weights -> transposed bf16 hi/lo rows of Wt[8192][2048].
// which = by>>6: 0=W_Q(h) 1=W_K(h) 2=W_G(dense) 3=W_V(h)
// ---------------------------------------------------------------------------
__global__ __launch_bounds__(256) void cvtW4_kernel(
    const float* __restrict__ W0, const float* __restrict__ W1,
    const float* __restrict__ W2, const float* __restrict__ W3,
    short* __restrict__ hi, short* __restrict__ lo) {
    __shared__ float T[32][33];
    int which = blockIdx.y >> 6;
    int k0 = blockIdx.x * 32, n0 = (blockIdx.y & 63) * 32;
    const float* W = (which == 0) ? W0 : (which == 1) ? W1 : (which == 2) ? W2 : W3;
    int headed = (which != 2);
    int tx = threadIdx.x & 7, ty = threadIdx.x >> 3;
    const float* src;
    if (headed) {
        int head = n0 >> 7, d0 = n0 & 127;
        src = W + ((size_t)head * 2048 + (k0 + ty)) * 128 + d0 + tx * 4;
    } else {
        src = W + (size_t)(k0 + ty) * 2048 + n0 + tx * 4;
    }
    float4 v = *(const float4*)src;
    T[ty][tx * 4 + 0] = v.x;
    T[ty][tx * 4 + 1] = v.y;
    T[ty][tx * 4 + 2] = v.z;
    T[ty][tx * 4 + 3] = v.w;
    __syncthreads();
    int nl = ty, k4 = tx * 4;
    short h[4], l[4];
#pragma unroll
    for (int j = 0; j < 4; ++j) f2hilo(T[k4 + j][nl], h[j], l[j]);
    size_t off = (size_t)(which * 2048 + n0 + nl) * 2048 + k0 + k4;
    *(short4*)&hi[off] = make_short4(h[0], h[1], h[2], h[3]);
    *(short4*)&lo[off] = make_short4(l[0], l[1], l[2], l[3]);
}

// ---------------------------------------------------------------------------
// Single weight -> transposed bf16 hi/lo (W_O)
// ---------------------------------------------------------------------------
__global__ __launch_bounds__(256) void cvtWt_kernel(
    const float* __restrict__ W, short* __restrict__ hi, short* __restrict__ lo) {
    __shared__ float T[32][33];
    int k0 = blockIdx.x * 32, n0 = blockIdx.y * 32;
    int tx = threadIdx.x & 7, ty = threadIdx.x >> 3;
    const float* src = W + (size_t)(k0 + ty) * 2048 + n0 + tx * 4;
    float4 v = *(const float4*)src;
    T[ty][tx * 4 + 0] = v.x;
    T[ty][tx * 4 + 1] = v.y;
    T[ty][tx * 4 + 2] = v.z;
    T[ty][tx * 4 + 3] = v.w;
    __syncthreads();
    int nl = ty, k4 = tx * 4;
    short h[4], l[4];
#pragma unroll
    for (int j = 0; j < 4; ++j) f2hilo(T[k4 + j][nl], h[j], l[j]);
    size_t off = (size_t)(n0 + nl) * 2048 + k0 + k4;
    *(short4*)&hi[off] = make_short4(h[0], h[1], h[2], h[3]);
    *(short4*)&lo[off] = make_short4(l[0], l[1], l[2], l[3]);
}

// ---------------------------------------------------------------------------
// 256x256-tile split-bf16 GEMM, BK=32, 512 thr (8 waves 2Mx4N), double-buffered
// LDS (128 KiB) with 2-deep counted-vmcnt pipeline + raw barriers + setprio.
// C[M][N](ldC) = (Ahi+Alo)[M][2048] x Bt[N][2048]^T. grid = (N/256, M/256).
// ---------------------------------------------------------------------------
__global__ __launch_bounds__(512, 2) void gemm256_kernel(
    const short* __restrict__ Ahi, const short* __restrict__ Alo,
    const short* __restrict__ Bhi, const short* __restrict__ Blo,
    float* __restrict__ C, int ldC) {
    // per buffer (32768 shorts): Ahi[4][256][8] @0, Alo @8192, Bhi @16384, Blo @24576
    __shared__ short lds[2 * 32768];

    int tid = threadIdx.x;
    int w = tid >> 6, lane = tid & 63;
    int lr = lane & 15, lk = lane >> 4;

    int ntx = gridDim.x;
    int nwg = ntx * gridDim.y;                 // multiple of 8
    int bid = blockIdx.y * ntx + blockIdx.x;
    int swz = (bid & 7) * (nwg >> 3) + (bid >> 3);
    int row0 = (swz / ntx) * 256, col0 = (swz % ntx) * 256;

    int wm = w >> 2, wn = w & 3;

    // staging sources: set i in {0,1}: e = i*512 + tid, kblk=e>>8, row=e&255
    const short* gah[2]; const short* gal[2];
    const short* gbh[2]; const short* gbl[2];
#pragma unroll
    for (int i = 0; i < 2; ++i) {
        int e = i * 512 + tid;
        int kblk = e >> 8, row = e & 255;
        size_t ao = (size_t)(row0 + row) * 2048 + kblk * 8;
        size_t bo = (size_t)(col0 + row) * 2048 + kblk * 8;
        gah[i] = Ahi + ao; gal[i] = Alo + ao;
        gbh[i] = Bhi + bo; gbl[i] = Blo + bo;
    }

    auto stage = [&](int buf, int kt) {
        const int ko = kt * 32;
        short* bse = &lds[buf * 32768];
#pragma unroll
        for (int i = 0; i < 2; ++i) {
            const int doff = (i * 512 + w * 64) * 8;   // wave-uniform dest
            gload16(gah[i] + ko, bse + doff);
            gload16(gal[i] + ko, bse + 8192 + doff);
            gload16(gbh[i] + ko, bse + 16384 + doff);
            gload16(gbl[i] + ko, bse + 24576 + doff);
        }
    };

    f32x4 acc[8][4] = {};

    stage(0, 0);
    for (int kt = 0; kt < 64; ++kt) {
        int buf = kt & 1;
        if (kt < 63) {
            stage(buf ^ 1, kt + 1);
            asm volatile("s_waitcnt vmcnt(8)" ::: "memory");
        } else {
            asm volatile("s_waitcnt vmcnt(0)" ::: "memory");
        }
        __builtin_amdgcn_s_barrier();
        __builtin_amdgcn_sched_barrier(0);

        const short* lb = &lds[buf * 32768];
        bf16x8 bh[4], bl[4];
#pragma unroll
        for (int n = 0; n < 4; ++n) {
            int roff = (lk * 256 + wn * 64 + n * 16 + lr) * 8;
            bh[n] = *(const bf16x8*)(lb + 16384 + roff);
            bl[n] = *(const bf16x8*)(lb + 24576 + roff);
        }
#pragma unroll
        for (int mc = 0; mc < 2; ++mc) {
            bf16x8 ah[4], al[4];
#pragma unroll
            for (int mi = 0; mi < 4; ++mi) {
                int roff = (lk * 256 + wm * 128 + (mc * 4 + mi) * 16 + lr) * 8;
                ah[mi] = *(const bf16x8*)(lb + roff);
                al[mi] = *(const bf16x8*)(lb + 8192 + roff);
            }
            __builtin_amdgcn_s_setprio(1);
#pragma unroll
            for (int mi = 0; mi < 4; ++mi)
#pragma unroll
                for (int n = 0; n < 4; ++n) {
                    int m = mc * 4 + mi;
                    acc[m][n] = __builtin_amdgcn_mfma_f32_16x16x32_bf16(ah[mi], bh[n], acc[m][n], 0, 0, 0);
                    acc[m][n] = __builtin_amdgcn_mfma_f32_16x16x32_bf16(ah[mi], bl[n], acc[m][n], 0, 0, 0);
                    acc[m][n] = __builtin_amdgcn_mfma_f32_16x16x32_bf16(al[mi], bh[n], acc[m][n], 0, 0, 0);
                }
            __builtin_amdgcn_s_setprio(0);
        }
        __builtin_amdgcn_sched_barrier(0);
        __builtin_amdgcn_s_barrier();
        __builtin_amdgcn_sched_barrier(0);
    }

    // D layout: col = lane&15, row = (lane>>4)*4 + i
#pragma unroll
    for (int m = 0; m < 8; ++m)
#pragma unroll
        for (int n = 0; n < 4; ++n) {
            int row = row0 + wm * 128 + m * 16 + lk * 4;
            int col = col0 + wn * 64 + n * 16 + lr;
            float* cp = &C[(size_t)row * ldC + col];
            cp[0 * (size_t)ldC] = acc[m][n][0];
            cp[1 * (size_t)ldC] = acc[m][n][1];
            cp[2 * (size_t)ldC] = acc[m][n][2];
            cp[3 * (size_t)ldC] = acc[m][n][3];
        }
}

// ---------------------------------------------------------------------------
// 128x128-tile split-bf16 GEMM, BK=32, 256 thr (4 waves 2x2), dbuf 2-deep
// counted-vmcnt pipeline. grid = (N/128, M/128).
// ---------------------------------------------------------------------------
__global__ __launch_bounds__(256) void gemm128_kernel(
    const short* __restrict__ Ahi, const short* __restrict__ Alo,
    const short* __restrict__ Bhi, const short* __restrict__ Blo,
    float* __restrict__ C, int ldC) {
    // per buffer (16384 shorts): Ahi[4][128][8] @0, Alo @4096, Bhi @8192, Blo @12288
    __shared__ short lds[2 * 16384];

    int tid = threadIdx.x;
    int w = tid >> 6, lane = tid & 63;
    int lr = lane & 15, lk = lane >> 4;

    int ntx = gridDim.x;
    int nwg = ntx * gridDim.y;
    int bid = blockIdx.y * ntx + blockIdx.x;
    int swz = (bid & 7) * (nwg >> 3) + (bid >> 3);
    int row0 = (swz / ntx) * 128, col0 = (swz % ntx) * 128;

    int wr = w >> 1, wc = w & 1;

    const short* gah[2]; const short* gal[2];
    const short* gbh[2]; const short* gbl[2];
#pragma unroll
    for (int i = 0; i < 2; ++i) {
        int e = i * 256 + tid;
        int kblk = e >> 7, row = e & 127;
        size_t ao = (size_t)(row0 + row) * 2048 + kblk * 8;
        size_t bo = (size_t)(col0 + row) * 2048 + kblk * 8;
        gah[i] = Ahi + ao; gal[i] = Alo + ao;
        gbh[i] = Bhi + bo; gbl[i] = Blo + bo;
    }

    auto stage = [&](int buf, int kt) {
        const int ko = kt * 32;
        short* bse = &lds[buf * 16384];
#pragma unroll
        for (int i = 0; i < 2; ++i) {
            const int doff = (i * 256 + w * 64) * 8;
            gload16(gah[i] + ko, bse + doff);
            gload16(gal[i] + ko, bse + 4096 + doff);
            gload16(gbh[i] + ko, bse + 8192 + doff);
            gload16(gbl[i] + ko, bse + 12288 + doff);
        }
    };

    f32x4 acc[4][4] = {};
    int abase = (lk * 128 + wr * 64 + lr) * 8;
    int bbase = (lk * 128 + wc * 64 + lr) * 8;

    stage(0, 0);
    for (int kt = 0; kt < 64; ++kt) {
        int buf = kt & 1;
        if (kt < 63) {
            stage(buf ^ 1, kt + 1);
            asm volatile("s_waitcnt vmcnt(8)" ::: "memory");
        } else {
            asm volatile("s_waitcnt vmcnt(0)" ::: "memory");
        }
        __builtin_amdgcn_s_barrier();
        __builtin_amdgcn_sched_barrier(0);

        const short* lb = &lds[buf * 16384];
        bf16x8 ah[4], al[4], bh[4], bl[4];
#pragma unroll
        for (int m = 0; m < 4; ++m) {
            ah[m] = *(const bf16x8*)(lb + abase + m * 128);
            al[m] = *(const bf16x8*)(lb + 4096 + abase + m * 128);
        }
#pragma unroll
        for (int n = 0; n < 4; ++n) {
            bh[n] = *(const bf16x8*)(lb + 8192 + bbase + n * 128);
            bl[n] = *(const bf16x8*)(lb + 12288 + bbase + n * 128);
        }
        __builtin_amdgcn_s_setprio(1);
#pragma unroll
        for (int m = 0; m < 4; ++m)
#pragma unroll
            for (int n = 0; n < 4; ++n) {
                acc[m][n] = __builtin_amdgcn_mfma_f32_16x16x32_bf16(ah[m], bh[n], acc[m][n], 0, 0, 0);
                acc[m][n] = __builtin_amdgcn_mfma_f32_16x16x32_bf16(ah[m], bl[n], acc[m][n], 0, 0, 0);
                acc[m][n] = __builtin_amdgcn_mfma_f32_16x16x32_bf16(al[m], bh[n], acc[m][n], 0, 0, 0);
            }
        __builtin_amdgcn_s_setprio(0);
        __builtin_amdgcn_sched_barrier(0);
        __builtin_amdgcn_s_barrier();
        __builtin_amdgcn_sched_barrier(0);
    }

#pragma unroll
    for (int m = 0; m < 4; ++m)
#pragma unroll
        for (int n = 0; n < 4; ++n) {
            int row = row0 + (wr << 6) + (m << 4) + (lk << 2);
            int col = col0 + (wc << 6) + (n << 4) + lr;
            float* cp = &C[(size_t)row * ldC + col];
            cp[0 * (size_t)ldC] = acc[m][n][0];
            cp[1 * (size_t)ldC] = acc[m][n][1];
            cp[2 * (size_t)ldC] = acc[m][n][2];
            cp[3 * (size_t)ldC] = acc[m][n][3];
        }
}

// ---------------------------------------------------------------------------
// Transpose-convert V: src fp32 [2048][2048] (ld 8192) -> dst bf16 [v][bs]
// ---------------------------------------------------------------------------
__global__ __launch_bounds__(256) void tcvt_kernel(
    const float* __restrict__ src, short* __restrict__ dst) {
    __shared__ float T[32][33];
    int r0 = blockIdx.x * 32;   // bs
    int c0 = blockIdx.y * 32;   // v
    int tx = threadIdx.x & 7, ty = threadIdx.x >> 3;
    float4 v = *(const float4*)&src[(size_t)(r0 + ty) * 8192 + c0 + tx * 4];
    T[ty][tx * 4 + 0] = v.x;
    T[ty][tx * 4 + 1] = v.y;
    T[ty][tx * 4 + 2] = v.z;
    T[ty][tx * 4 + 3] = v.w;
    __syncthreads();
    short4 o;
    o.x = __builtin_bit_cast(short, (__bf16)T[tx * 4 + 0][ty]);
    o.y = __builtin_bit_cast(short, (__bf16)T[tx * 4 + 1][ty]);
    o.z = __builtin_bit_cast(short, (__bf16)T[tx * 4 + 2][ty]);
    o.w = __builtin_bit_cast(short, (__bf16)T[tx * 4 + 3][ty]);
    *(short4*)&dst[(size_t)(c0 + ty) * 2048 + r0 + tx * 4] = o;
}

// ---------------------------------------------------------------------------
// xPos rotary: read Q,K fp32 from QKGV (ld 8192), write split-bf16 Q,K
// ---------------------------------------------------------------------------
__global__ void xpos_kernel(const float* __restrict__ QKGV,
                            short* __restrict__ Qhi, short* __restrict__ Qlo,
                            short* __restrict__ Khi, short* __restrict__ Klo,
                            const float* __restrict__ sinT,
                            const float* __restrict__ cosT,
                            const float* __restrict__ scaleT) {
    int chunk = blockIdx.x * 256 + threadIdx.x;
    int which = blockIdx.y;                        // 0=Q, 1=K
    int row = chunk >> 9;
    int c = (chunk & 511) << 2;
    int s = row & (S_ - 1);
    int j = (c & 127) >> 1;
    float4 x = *(const float4*)&QKGV[(size_t)row * 8192 + which * 2048 + c];
    int tb = s * 64 + j;
    float sc0 = scaleT[tb], sc1 = scaleT[tb + 1];
    if (which) { sc0 = 1.0f / sc0; sc1 = 1.0f / sc1; }
    float c0 = cosT[tb] * sc0,     s0 = sinT[tb] * sc0;
    float c1 = cosT[tb + 1] * sc1, s1 = sinT[tb + 1] * sc1;
    float4 y;
    y.x = x.x * c0 - x.y * s0;
    y.y = x.y * c0 + x.x * s0;
    y.z = x.z * c1 - x.w * s1;
    y.w = x.w * c1 + x.z * s1;
    short* hi = which ? Khi : Qhi;
    short* lo = which ? Klo : Qlo;
    short h[4], l[4];
    f2hilo(y.x, h[0], l[0]);
    f2hilo(y.y, h[1], l[1]);
    f2hilo(y.z, h[2], l[2]);
    f2hilo(y.w, h[3], l[3]);
    *(short4*)&hi[(size_t)row * 2048 + c] = make_short4(h[0], h[1], h[2], h[3]);
    *(short4*)&lo[(size_t)row * 2048 + c] = make_short4(l[0], l[1], l[2], l[3]);
}

// ---------------------------------------------------------------------------
// MFMA retention (unchanged structure; Y ld 8192)
// ---------------------------------------------------------------------------
__global__ __launch_bounds__(512) void retention_mfma_kernel(
    const short* __restrict__ Qhi, const short* __restrict__ Qlo,
    const short* __restrict__ Khi, const short* __restrict__ Klo,
    const short* __restrict__ Vtb, float* __restrict__ Y /* ld 8192 */) {
    __shared__ short KldsH[8192];
    __shared__ short KldsL[8192];
    __shared__ short Vlds[8192];
    __shared__ short Slds[8 * 544];

    int tid = threadIdx.x;
    int w = tid >> 6, lane = tid & 63;
    int lr = lane & 15, lk = lane >> 4;
    int bn = blockIdx.y;
    int b = bn >> 4, n = bn & 15;

    const float l0 = -3.4657359027997265f;
    const float l1 = -6.2383246250395077f;
    float gamma = 1.0f - expf(l0 + (l1 - l0) * (float)n * (1.0f / 15.0f));
    float log2g = log2f(gamma);

    int sh = (w & 1) * 32;
    int tq = (w >> 1) * 16;
    int vq = (w >> 1) * 32;

    for (int pass = 0; pass < 2; ++pass) {
        int sTile = pass ? (15 - (int)blockIdx.x) : (int)blockIdx.x;
        int s0 = sTile * 64;

        bf16x8 qh[2][4], ql[2][4];
#pragma unroll
        for (int m = 0; m < 2; ++m)
#pragma unroll
            for (int ks = 0; ks < 4; ++ks) {
                size_t off = (size_t)(b * S_ + s0 + sh + m * 16 + lr) * 2048
                           + n * 128 + ks * 32 + lk * 8;
                qh[m][ks] = *(const bf16x8*)&Qhi[off];
                ql[m][ks] = *(const bf16x8*)&Qlo[off];
            }

        f32x4 yacc[2][2] = {};

        for (int t0 = 0; t0 <= s0; t0 += 64) {
#pragma unroll
            for (int i = 0; i < 2; ++i) {
                int e = i * 512 + tid;
                int kb = e >> 6, traw = e & 63;
                int t = traw ^ ((kb & 3) << 1);
                size_t koff = (size_t)(b * S_ + t0 + t) * 2048 + n * 128 + kb * 8;
                short* dst = &KldsH[(i * 512 + w * 64) * 8];
                gload16(Khi + koff, dst);
                short* dstl = &KldsL[(i * 512 + w * 64) * 8];
                gload16(Klo + koff, dstl);
                int tb = e >> 7, vraw = e & 127;
                int v = vraw ^ ((tb & 3) << 1);
                size_t voff = (size_t)(n * 128 + v) * 2048 + b * S_ + t0 + tb * 8;
                short* dstv = &Vlds[(i * 512 + w * 64) * 8];
                gload16(Vtb + voff, dstv);
            }
            __syncthreads();

            f32x4 sacc[2] = {};
#pragma unroll
            for (int ks = 0; ks < 4; ++ks) {
                int kb = ks * 4 + lk;
                int entry = kb * 64 + ((tq + lr) ^ ((kb & 3) << 1));
                bf16x8 kh = *(const bf16x8*)&KldsH[entry * 8];
                bf16x8 kl = *(const bf16x8*)&KldsL[entry * 8];
#pragma unroll
                for (int m = 0; m < 2; ++m) {
                    sacc[m] = __builtin_amdgcn_mfma_f32_16x16x32_bf16(qh[m][ks], kh, sacc[m], 0, 0, 0);
                    sacc[m] = __builtin_amdgcn_mfma_f32_16x16x32_bf16(qh[m][ks], kl, sacc[m], 0, 0, 0);
                    sacc[m] = __builtin_amdgcn_mfma_f32_16x16x32_bf16(ql[m][ks], kh, sacc[m], 0, 0, 0);
                }
            }

            int t_loc = tq + lr;
            bool diag = (t0 == s0);
#pragma unroll
            for (int m = 0; m < 2; ++m)
#pragma unroll
                for (int i = 0; i < 4; ++i) {
                    int s_loc = sh + m * 16 + lk * 4 + i;
                    int dt = (s0 + s_loc) - (t0 + t_loc);
                    float wgt = exp2f((float)dt * log2g);
                    if (diag && dt < 0) wgt = 0.0f;
                    float val = sacc[m][i] * wgt;
                    Slds[(t_loc >> 3) * 544 + s_loc * 8 + (t_loc & 7)] =
                        __builtin_bit_cast(short, (__bf16)val);
                }
            __syncthreads();

#pragma unroll
            for (int kt = 0; kt < 2; ++kt) {
                int kb = kt * 4 + lk;
                bf16x8 vf[2], sf[2];
#pragma unroll
                for (int m2 = 0; m2 < 2; ++m2) {
                    int v = vq + m2 * 16 + lr;
                    vf[m2] = *(const bf16x8*)&Vlds[(kb * 128 + (v ^ ((kb & 3) << 1))) * 8];
                }
#pragma unroll
                for (int n2 = 0; n2 < 2; ++n2) {
                    int scol = sh + n2 * 16 + lr;
                    sf[n2] = *(const bf16x8*)&Slds[kb * 544 + scol * 8];
                }
#pragma unroll
                for (int m2 = 0; m2 < 2; ++m2)
#pragma unroll
                    for (int n2 = 0; n2 < 2; ++n2)
                        yacc[m2][n2] = __builtin_amdgcn_mfma_f32_16x16x32_bf16(
                            vf[m2], sf[n2], yacc[m2][n2], 0, 0, 0);
            }
            __syncthreads();
        }

#pragma unroll
        for (int m2 = 0; m2 < 2; ++m2)
#pragma unroll
            for (int n2 = 0; n2 < 2; ++n2) {
                int srow = b * S_ + s0 + sh + n2 * 16 + lr;
                int vcol = n * 128 + vq + m2 * 16 + lk * 4;
                f32x4 v = yacc[m2][n2];
                *(float4*)&Y[(size_t)srow * 8192 + vcol] =
                    make_float4(v[0], v[1], v[2], v[3]);
            }
    }
}

// ---------------------------------------------------------------------------
// GroupNorm(16x128) + SiLU gate -> split-bf16 Z. Y,G at ld 8192.
// ---------------------------------------------------------------------------
__global__ __launch_bounds__(256) void gn_gate_kernel(
    const float* __restrict__ Y, const float* __restrict__ G,
    const float* __restrict__ gnw, const float* __restrict__ gnb,
    short* __restrict__ Zhi, short* __restrict__ Zlo) {
    int row = blockIdx.x;
    int lane = threadIdx.x & 63;
    int wave = threadIdx.x >> 6;
    const float* yrow = Y + (size_t)row * 8192;
    const float* grow = G + (size_t)row * 8192;
    size_t zoff = (size_t)row * 2048;

    for (int g = wave * 4; g < wave * 4 + 4; ++g) {
        float y0 = yrow[g * 128 + lane];
        float y1 = yrow[g * 128 + 64 + lane];
        float sum = y0 + y1;
#pragma unroll
        for (int m = 32; m >= 1; m >>= 1) sum += __shfl_xor(sum, m, 64);
        float mean = sum * (1.0f / 128.0f);
        float d0 = y0 - mean, d1 = y1 - mean;
        float vs = d0 * d0 + d1 * d1;
#pragma unroll
        for (int m = 32; m >= 1; m >>= 1) vs += __shfl_xor(vs, m, 64);
        float rinv = rsqrtf(vs * (1.0f / 128.0f) + 1e-5f);
        int h0 = g * 128 + lane, h1 = h0 + 64;
        float yn0 = d0 * rinv * gnw[h0] + gnb[h0];
        float yn1 = d1 * rinv * gnw[h1] + gnb[h1];
        float gv0 = grow[h0], gv1 = grow[h1];
        float z0 = (gv0 / (1.0f + expf(-gv0))) * yn0;
        float z1 = (gv1 / (1.0f + expf(-gv1))) * yn1;
        short h, l;
        f2hilo(z0, h, l); Zhi[zoff + h0] = h; Zlo[zoff + h0] = l;
        f2hilo(z1, h, l); Zhi[zoff + h1] = h; Zlo[zoff + h1] = l;
    }
}

// ---------------------------------------------------------------------------
extern "C" void kernel_launch(void* const* d_in, const int* in_sizes, int n_in,
                              void* d_out, int out_size, void* d_ws, size_t ws_size,
                              hipStream_t stream) {
    const float* X   = (const float*)d_in[0];
    const float* W_Q = (const float*)d_in[1];
    const float* W_K = (const float*)d_in[2];
    const float* W_V = (const float*)d_in[3];
    const float* W_G = (const float*)d_in[4];
    const float* W_O = (const float*)d_in[5];
    const float* gnw = (const float*)d_in[6];
    const float* gnb = (const float*)d_in[7];
    float* out = (float*)d_out;
    float* ws  = (float*)d_ws;

    // Workspace (float offsets):
    // [0,1): Xhi/Xlo   [1,3): Wthi (8192x2048 sh)   [3,5): Wtlo   [5,9): QKGV fp32
    // [9,+): tables.  After QKGV GEMM, dead regions are reused:
    //   Qhi/Qlo <- Xhi/Xlo;  Khi/Klo/Vtb <- Wthi rows 2048..8191;
    //   Zhi/Zlo <- Wtlo rows 2048..6143.  W_O cvt refills rows 0..2047.
    short* Xhi  = (short*)ws;
    short* Xlo  = Xhi + MATF;
    short* Wthi = (short*)(ws + MATF);
    short* Wtlo = Wthi + 4 * MATF;
    float* QKGV = ws + 5 * MATF;          // Q:0..2047 K:2048.. G:4096.. V:6144..
    float* sinT   = ws + 9 * MATF;
    float* cosT   = sinT + S_ * 64;
    float* scaleT = cosT + S_ * 64;

    short* Qhi = Xhi;
    short* Qlo = Xlo;
    short* Khi = Wthi + (size_t)2048 * 2048;
    short* Klo = Wthi + (size_t)4096 * 2048;
    short* Vtb = Wthi + (size_t)6144 * 2048;
    short* Zhi = Wtlo + (size_t)2048 * 2048;
    short* Zlo = Wtlo + (size_t)4096 * 2048;

    tables_kernel<<<256, 256, 0, stream>>>(sinT, cosT, scaleT);
    cvt_hilo_kernel<<<4096, 256, 0, stream>>>(X, Xhi, Xlo);
    cvtW4_kernel<<<dim3(64, 256), 256, 0, stream>>>(W_Q, W_K, W_G, W_V, Wthi, Wtlo);

    // Fused Q/K/G/V projection: 2048 x 8192, grid 32x8 = 256 wgs (1/CU)
    gemm256_kernel<<<dim3(32, 8), 512, 0, stream>>>(Xhi, Xlo, Wthi, Wtlo, QKGV, 8192);

    // V^T bf16 from QKGV cols 6144..8191
    tcvt_kernel<<<dim3(64, 64), 256, 0, stream>>>(QKGV + 6144, Vtb);

    xpos_kernel<<<dim3(4096, 2), 256, 0, stream>>>(QKGV, Qhi, Qlo, Khi, Klo, sinT, cosT, scaleT);

    // W_O convert (Wt rows 0..2047 are free after the QKGV GEMM)
    cvtWt_kernel<<<dim3(64, 64), 256, 0, stream>>>(W_O, Wthi, Wtlo);

    // Retention: Y -> QKGV cols 0..2047 (Q fp32 dead after xpos)
    retention_mfma_kernel<<<dim3(8, 32), 512, 0, stream>>>(Qhi, Qlo, Khi, Klo, Vtb, QKGV);

    gn_gate_kernel<<<BS_, 256, 0, stream>>>(QKGV, QKGV + 4096, gnw, gnb, Zhi, Zlo);

    // Output GEMM: 2048x2048, grid 16x16 = 256 wgs
    gemm128_kernel<<<dim3(16, 16), 256, 0, stream>>>(Zhi, Zlo, Wthi, Wtlo, out, 2048);
}

// Round 5
// 414.030 us; speedup vs baseline: 5.0898x; 1.5522x over previous
//
#include <hip/hip_runtime.h>
#include <math.h>

// Shapes (fixed): B=2, S=1024, H=2048, nheads=16, d=128
#define S_     1024
#define H_     2048
#define BS_    2048
#define MATF   ((size_t)BS_ * H_)    // 4,194,304 elements (2048x2048)

typedef __bf16 bf16x8 __attribute__((ext_vector_type(8)));
typedef float  f32x4  __attribute__((ext_vector_type(4)));

__device__ __forceinline__ void f2hilo(float x, short& h, short& l) {
    __bf16 bh = (__bf16)x;
    float  r  = x - (float)bh;
    __bf16 bl = (__bf16)r;
    h = __builtin_bit_cast(short, bh);
    l = __builtin_bit_cast(short, bl);
}

__device__ __forceinline__ short f2b(float x) {
    return __builtin_bit_cast(short, (__bf16)x);
}

__device__ __forceinline__ void gload16(const void* g, void* l) {
    __builtin_amdgcn_global_load_lds(
        (const __attribute__((address_space(1))) void*)g,
        (__attribute__((address_space(3))) void*)l, 16, 0, 0);
}

// ---------------------------------------------------------------------------
// xPos tables: sin/cos/scale, each [S][64]
// ---------------------------------------------------------------------------
__global__ void tables_kernel(float* __restrict__ sinT, float* __restrict__ cosT,
                              float* __restrict__ scaleT) {
    int idx = blockIdx.x * 256 + threadIdx.x;
    int s = idx >> 6, j = idx & 63;
    float xscale   = (2.0f * j + 0.4f * 128.0f) / (1.4f * 128.0f);
    float sc       = powf(xscale, (float)s * (1.0f / 512.0f));
    float inv_freq = powf(10000.0f, -(float)j * (1.0f / 64.0f));
    float ang      = (float)s * inv_freq;
    sinT[idx]   = sinf(ang);
    cosT[idx]   = cosf(ang);
    scaleT[idx] = sc;
}

// ---------------------------------------------------------------------------
// fp32 -> bf16 hi/lo split, elementwise (X)
// ---------------------------------------------------------------------------
__global__ __launch_bounds__(256) void cvt_hilo_kernel(
    const float* __restrict__ src, short* __restrict__ hi, short* __restrict__ lo) {
    int i = blockIdx.x * 256 + threadIdx.x;
    float4 v = *(const float4*)&src[(size_t)i * 4];
    short h[4], l[4];
    f2hilo(v.x, h[0], l[0]);
    f2hilo(v.y, h[1], l[1]);
    f2hilo(v.z, h[2], l[2]);
    f2hilo(v.w, h[3], l[3]);
    *(short4*)&hi[(size_t)i * 4] = make_short4(h[0], h[1], h[2], h[3]);
    *(short4*)&lo[(size_t)i * 4] = make_short4(l[0], l[1], l[2], l[3]);
}

// ---------------------------------------------------------------------------
// All 5 weights -> transposed plain-bf16 rows of Wt[5*2048][2048].
// which = by>>6: 0=W_Q(h) 1=W_K(h) 2=W_G(dense) 3=W_V(h) 4=W_O(dense)
// ---------------------------------------------------------------------------
__global__ __launch_bounds__(256) void cvtW5_kernel(
    const float* __restrict__ W0, const float* __restrict__ W1,
    const float* __restrict__ W2, const float* __restrict__ W3,
    const float* __restrict__ W4, short* __restrict__ Wt) {
    __shared__ float T[32][33];
    int which = blockIdx.y >> 6;
    int k0 = blockIdx.x * 32, n0 = (blockIdx.y & 63) * 32;
    const float* W = (which == 0) ? W0 : (which == 1) ? W1 :
                     (which == 2) ? W2 : (which == 3) ? W3 : W4;
    int headed = (which != 2 && which != 4);
    int tx = threadIdx.x & 7, ty = threadIdx.x >> 3;
    const float* src;
    if (headed) {
        int head = n0 >> 7, d0 = n0 & 127;
        src = W + ((size_t)head * 2048 + (k0 + ty)) * 128 + d0 + tx * 4;
    } else {
        src = W + (size_t)(k0 + ty) * 2048 + n0 + tx * 4;
    }
    float4 v = *(const float4*)src;
    T[ty][tx * 4 + 0] = v.x;
    T[ty][tx * 4 + 1] = v.y;
    T[ty][tx * 4 + 2] = v.z;
    T[ty][tx * 4 + 3] = v.w;
    __syncthreads();
    int nl = ty, k4 = tx * 4;
    short4 o;
    o.x = f2b(T[k4 + 0][nl]);
    o.y = f2b(T[k4 + 1][nl]);
    o.z = f2b(T[k4 + 2][nl]);
    o.w = f2b(T[k4 + 3][nl]);
    *(short4*)&Wt[(size_t)(which * 2048 + n0 + nl) * 2048 + k0 + k4] = o;
}

// ---------------------------------------------------------------------------
// Phased 256x256 2-term GEMM: C = (Ahi+Alo)[2048-K] x Bt^T.  512 thr, 8 waves
// (2Mx4N), BK=32, triple-buffered LDS (3 x 48 KiB), 2-deep prefetch,
// counted vmcnt(6), 4 phases/K-step {ds_read || stage -> bar -> lgkm -> 16 MFMA -> bar}.
// grid: 8 M-panels x 32 N-panels = 256 blocks; XCD 2D regions 4Mx8N.
// ---------------------------------------------------------------------------
#define G256_PHASE(P, ...)                                                     \
    {                                                                          \
        int ra = so + ((lk << 8) + wm * 128 + (2 * (P)) * 16 + lr) * 8;        \
        bf16x8 a0h = *(const bf16x8*)&lds[ra];                                 \
        bf16x8 a0l = *(const bf16x8*)&lds[ra + 8192];                          \
        bf16x8 a1h = *(const bf16x8*)&lds[ra + 128];                           \
        bf16x8 a1l = *(const bf16x8*)&lds[ra + 8192 + 128];                    \
        if ((P) == 0) {                                                        \
            _Pragma("unroll")                                                  \
            for (int n = 0; n < 4; ++n)                                        \
                bh[n] = *(const bf16x8*)&lds[so + 16384 +                      \
                         ((lk << 8) + wn * 64 + n * 16 + lr) * 8];             \
        }                                                                      \
        __VA_ARGS__;                                                           \
        __builtin_amdgcn_s_barrier();                                          \
        asm volatile("s_waitcnt lgkmcnt(0)" ::: "memory");                     \
        __builtin_amdgcn_sched_barrier(0);                                     \
        __builtin_amdgcn_s_setprio(1);                                         \
        _Pragma("unroll")                                                      \
        for (int n = 0; n < 4; ++n) {                                          \
            acc[2*(P)][n]   = __builtin_amdgcn_mfma_f32_16x16x32_bf16(a0h, bh[n], acc[2*(P)][n], 0, 0, 0);   \
            acc[2*(P)][n]   = __builtin_amdgcn_mfma_f32_16x16x32_bf16(a0l, bh[n], acc[2*(P)][n], 0, 0, 0);   \
            acc[2*(P)+1][n] = __builtin_amdgcn_mfma_f32_16x16x32_bf16(a1h, bh[n], acc[2*(P)+1][n], 0, 0, 0); \
            acc[2*(P)+1][n] = __builtin_amdgcn_mfma_f32_16x16x32_bf16(a1l, bh[n], acc[2*(P)+1][n], 0, 0, 0); \
        }                                                                      \
        __builtin_amdgcn_s_setprio(0);                                         \
        __builtin_amdgcn_s_barrier();                                          \
        __builtin_amdgcn_sched_barrier(0);                                     \
    }

__global__ __launch_bounds__(512) void gemm256p_kernel(
    const short* __restrict__ Ahi, const short* __restrict__ Alo,
    const short* __restrict__ Bt, float* __restrict__ C, int ldC) {
    // per buffer (24576 shorts): Ahi[4][256][8]@0, Alo@8192, B@16384
    __shared__ short lds[3 * 24576];

    int tid = threadIdx.x;
    int w = tid >> 6, lane = tid & 63;
    int lr = lane & 15, lk = lane >> 4;
    int wm = w >> 2, wn = w & 3;

    int bid = blockIdx.y * gridDim.x + blockIdx.x;   // 0..255
    int xcd = bid & 7, idx = bid >> 3;
    int row0 = ((xcd >> 2) * 4 + (idx >> 3)) * 256;  // 8 M-panels
    int col0 = ((xcd & 3) * 8 + (idx & 7)) * 256;    // 32 N-panels

    const short *gah[2], *gal[2], *gb[2];
#pragma unroll
    for (int i = 0; i < 2; ++i) {
        int e = i * 512 + tid;
        int kblk = e >> 8, row = e & 255;
        gah[i] = Ahi + (size_t)(row0 + row) * 2048 + kblk * 8;
        gal[i] = Alo + (size_t)(row0 + row) * 2048 + kblk * 8;
        gb[i]  = Bt  + (size_t)(col0 + row) * 2048 + kblk * 8;
    }
    const int dof0 = (w * 64) * 8;
    const int dof1 = (512 + w * 64) * 8;

    auto stagefull = [&](int buf, int kt) {
        int sb = buf * 24576, ko = kt * 32;
        gload16(gah[0] + ko, &lds[sb + dof0]);
        gload16(gah[1] + ko, &lds[sb + dof1]);
        gload16(gal[0] + ko, &lds[sb + 8192 + dof0]);
        gload16(gal[1] + ko, &lds[sb + 8192 + dof1]);
        gload16(gb[0] + ko,  &lds[sb + 16384 + dof0]);
        gload16(gb[1] + ko,  &lds[sb + 16384 + dof1]);
    };

    f32x4 acc[8][4] = {};
    bf16x8 bh[4];

    stagefull(0, 0);
    stagefull(1, 1);

    for (int kt = 0; kt < 64; ++kt) {
        int so = (kt % 3) * 24576;
        int sb2 = ((kt + 2) % 3) * 24576;
        int ko2 = (kt + 2) * 32;
        bool doStage = (kt < 62);

        if (kt < 63) asm volatile("s_waitcnt vmcnt(6)" ::: "memory");
        else         asm volatile("s_waitcnt vmcnt(0)" ::: "memory");
        __builtin_amdgcn_s_barrier();
        __builtin_amdgcn_sched_barrier(0);

        G256_PHASE(0,
            if (doStage) {
                gload16(gah[0] + ko2, &lds[sb2 + dof0]);
                gload16(gah[1] + ko2, &lds[sb2 + dof1]);
            })
        G256_PHASE(1,
            if (doStage) {
                gload16(gal[0] + ko2, &lds[sb2 + 8192 + dof0]);
                gload16(gal[1] + ko2, &lds[sb2 + 8192 + dof1]);
            })
        G256_PHASE(2,
            if (doStage) gload16(gb[0] + ko2, &lds[sb2 + 16384 + dof0]);)
        G256_PHASE(3,
            if (doStage) gload16(gb[1] + ko2, &lds[sb2 + 16384 + dof1]);)
    }

    // D layout: col = lane&15, row = (lane>>4)*4 + i
#pragma unroll
    for (int m = 0; m < 8; ++m)
#pragma unroll
        for (int n = 0; n < 4; ++n) {
            int row = row0 + wm * 128 + m * 16 + lk * 4;
            int col = col0 + wn * 64 + n * 16 + lr;
            float* cp = &C[(size_t)row * ldC + col];
            cp[0 * (size_t)ldC] = acc[m][n][0];
            cp[1 * (size_t)ldC] = acc[m][n][1];
            cp[2 * (size_t)ldC] = acc[m][n][2];
            cp[3 * (size_t)ldC] = acc[m][n][3];
        }
}

// ---------------------------------------------------------------------------
// Phased 128x128 2-term GEMM (out projection). 256 thr, 4 waves (2x2), BK=32,
// triple-buffered (3 x 24 KiB), 2 phases/K-step, counted vmcnt(6).
// grid 16x16 = 256 blocks; XCD regions 4Mx8N.
// ---------------------------------------------------------------------------
#define G128_PHASE(P, ...)                                                     \
    {                                                                          \
        int ra = so + ((lk << 7) + wr * 64 + (2 * (P)) * 16 + lr) * 8;         \
        bf16x8 a0h = *(const bf16x8*)&lds[ra];                                 \
        bf16x8 a0l = *(const bf16x8*)&lds[ra + 4096];                          \
        bf16x8 a1h = *(const bf16x8*)&lds[ra + 128];                           \
        bf16x8 a1l = *(const bf16x8*)&lds[ra + 4096 + 128];                    \
        if ((P) == 0) {                                                        \
            _Pragma("unroll")                                                  \
            for (int n = 0; n < 4; ++n)                                        \
                bh[n] = *(const bf16x8*)&lds[so + 8192 +                       \
                         ((lk << 7) + wc * 64 + n * 16 + lr) * 8];             \
        }                                                                      \
        __VA_ARGS__;                                                           \
        __builtin_amdgcn_s_barrier();                                          \
        asm volatile("s_waitcnt lgkmcnt(0)" ::: "memory");                     \
        __builtin_amdgcn_sched_barrier(0);                                     \
        __builtin_amdgcn_s_setprio(1);                                         \
        _Pragma("unroll")                                                      \
        for (int n = 0; n < 4; ++n) {                                          \
            acc[2*(P)][n]   = __builtin_amdgcn_mfma_f32_16x16x32_bf16(a0h, bh[n], acc[2*(P)][n], 0, 0, 0);   \
            acc[2*(P)][n]   = __builtin_amdgcn_mfma_f32_16x16x32_bf16(a0l, bh[n], acc[2*(P)][n], 0, 0, 0);   \
            acc[2*(P)+1][n] = __builtin_amdgcn_mfma_f32_16x16x32_bf16(a1h, bh[n], acc[2*(P)+1][n], 0, 0, 0); \
            acc[2*(P)+1][n] = __builtin_amdgcn_mfma_f32_16x16x32_bf16(a1l, bh[n], acc[2*(P)+1][n], 0, 0, 0); \
        }                                                                      \
        __builtin_amdgcn_s_setprio(0);                                         \
        __builtin_amdgcn_s_barrier();                                          \
        __builtin_amdgcn_sched_barrier(0);                                     \
    }

__global__ __launch_bounds__(256) void gemm128p_kernel(
    const short* __restrict__ Ahi, const short* __restrict__ Alo,
    const short* __restrict__ Bt, float* __restrict__ C, int ldC) {
    // per buffer (12288 shorts): Ahi[4][128][8]@0, Alo@4096, B@8192
    __shared__ short lds[3 * 12288];

    int tid = threadIdx.x;
    int w = tid >> 6, lane = tid & 63;
    int lr = lane & 15, lk = lane >> 4;
    int wr = w >> 1, wc = w & 1;

    int bid = blockIdx.y * gridDim.x + blockIdx.x;   // 0..255
    int xcd = bid & 7, idx = bid >> 3;
    int row0 = ((xcd >> 1) * 4 + (idx >> 3)) * 128;  // 16 M-panels
    int col0 = ((xcd & 1) * 8 + (idx & 7)) * 128;    // 16 N-panels

    const short *gah[2], *gal[2], *gb[2];
#pragma unroll
    for (int i = 0; i < 2; ++i) {
        int e = i * 256 + tid;
        int kblk = e >> 7, row = e & 127;
        gah[i] = Ahi + (size_t)(row0 + row) * 2048 + kblk * 8;
        gal[i] = Alo + (size_t)(row0 + row) * 2048 + kblk * 8;
        gb[i]  = Bt  + (size_t)(col0 + row) * 2048 + kblk * 8;
    }
    const int dof0 = (w * 64) * 8;
    const int dof1 = (256 + w * 64) * 8;

    auto stagefull = [&](int buf, int kt) {
        int sb = buf * 12288, ko = kt * 32;
        gload16(gah[0] + ko, &lds[sb + dof0]);
        gload16(gah[1] + ko, &lds[sb + dof1]);
        gload16(gal[0] + ko, &lds[sb + 4096 + dof0]);
        gload16(gal[1] + ko, &lds[sb + 4096 + dof1]);
        gload16(gb[0] + ko,  &lds[sb + 8192 + dof0]);
        gload16(gb[1] + ko,  &lds[sb + 8192 + dof1]);
    };

    f32x4 acc[4][4] = {};
    bf16x8 bh[4];

    stagefull(0, 0);
    stagefull(1, 1);

    for (int kt = 0; kt < 64; ++kt) {
        int so = (kt % 3) * 12288;
        int sb2 = ((kt + 2) % 3) * 12288;
        int ko2 = (kt + 2) * 32;
        bool doStage = (kt < 62);

        if (kt < 63) asm volatile("s_waitcnt vmcnt(6)" ::: "memory");
        else         asm volatile("s_waitcnt vmcnt(0)" ::: "memory");
        __builtin_amdgcn_s_barrier();
        __builtin_amdgcn_sched_barrier(0);

        G128_PHASE(0,
            if (doStage) {
                gload16(gah[0] + ko2, &lds[sb2 + dof0]);
                gload16(gah[1] + ko2, &lds[sb2 + dof1]);
                gload16(gal[0] + ko2, &lds[sb2 + 4096 + dof0]);
            })
        G128_PHASE(1,
            if (doStage) {
                gload16(gal[1] + ko2, &lds[sb2 + 4096 + dof1]);
                gload16(gb[0] + ko2,  &lds[sb2 + 8192 + dof0]);
                gload16(gb[1] + ko2,  &lds[sb2 + 8192 + dof1]);
            })
    }

#pragma unroll
    for (int m = 0; m < 4; ++m)
#pragma unroll
        for (int n = 0; n < 4; ++n) {
            int row = row0 + (wr << 6) + (m << 4) + (lk << 2);
            int col = col0 + (wc << 6) + (n << 4) + lr;
            float* cp = &C[(size_t)row * ldC + col];
            cp[0 * (size_t)ldC] = acc[m][n][0];
            cp[1 * (size_t)ldC] = acc[m][n][1];
            cp[2 * (size_t)ldC] = acc[m][n][2];
            cp[3 * (size_t)ldC] = acc[m][n][3];
        }
}

// ---------------------------------------------------------------------------
// Transpose-convert V: src fp32 (ld 8192) -> dst bf16 [v][bs]
// ---------------------------------------------------------------------------
__global__ __launch_bounds__(256) void tcvt_kernel(
    const float* __restrict__ src, short* __restrict__ dst) {
    __shared__ float T[32][33];
    int r0 = blockIdx.x * 32;   // bs
    int c0 = blockIdx.y * 32;   // v
    int tx = threadIdx.x & 7, ty = threadIdx.x >> 3;
    float4 v = *(const float4*)&src[(size_t)(r0 + ty) * 8192 + c0 + tx * 4];
    T[ty][tx * 4 + 0] = v.x;
    T[ty][tx * 4 + 1] = v.y;
    T[ty][tx * 4 + 2] = v.z;
    T[ty][tx * 4 + 3] = v.w;
    __syncthreads();
    short4 o;
    o.x = f2b(T[tx * 4 + 0][ty]);
    o.y = f2b(T[tx * 4 + 1][ty]);
    o.z = f2b(T[tx * 4 + 2][ty]);
    o.w = f2b(T[tx * 4 + 3][ty]);
    *(short4*)&dst[(size_t)(c0 + ty) * 2048 + r0 + tx * 4] = o;
}

// ---------------------------------------------------------------------------
// xPos rotary: read Q,K fp32 from QKGV (ld 8192);
// Q -> split-bf16 (hi/lo); K -> plain bf16.
// ---------------------------------------------------------------------------
__global__ void xpos_kernel(const float* __restrict__ QKGV,
                            short* __restrict__ Qhi, short* __restrict__ Qlo,
                            short* __restrict__ Kb,
                            const float* __restrict__ sinT,
                            const float* __restrict__ cosT,
                            const float* __restrict__ scaleT) {
    int chunk = blockIdx.x * 256 + threadIdx.x;
    int which = blockIdx.y;                        // 0=Q, 1=K
    int row = chunk >> 9;
    int c = (chunk & 511) << 2;
    int s = row & (S_ - 1);
    int j = (c & 127) >> 1;
    float4 x = *(const float4*)&QKGV[(size_t)row * 8192 + which * 2048 + c];
    int tb = s * 64 + j;
    float sc0 = scaleT[tb], sc1 = scaleT[tb + 1];
    if (which) { sc0 = 1.0f / sc0; sc1 = 1.0f / sc1; }
    float c0 = cosT[tb] * sc0,     s0 = sinT[tb] * sc0;
    float c1 = cosT[tb + 1] * sc1, s1 = sinT[tb + 1] * sc1;
    float4 y;
    y.x = x.x * c0 - x.y * s0;
    y.y = x.y * c0 + x.x * s0;
    y.z = x.z * c1 - x.w * s1;
    y.w = x.w * c1 + x.z * s1;
    if (which == 0) {
        short h[4], l[4];
        f2hilo(y.x, h[0], l[0]);
        f2hilo(y.y, h[1], l[1]);
        f2hilo(y.z, h[2], l[2]);
        f2hilo(y.w, h[3], l[3]);
        *(short4*)&Qhi[(size_t)row * 2048 + c] = make_short4(h[0], h[1], h[2], h[3]);
        *(short4*)&Qlo[(size_t)row * 2048 + c] = make_short4(l[0], l[1], l[2], l[3]);
    } else {
        short4 o;
        o.x = f2b(y.x); o.y = f2b(y.y); o.z = f2b(y.z); o.w = f2b(y.w);
        *(short4*)&Kb[(size_t)row * 2048 + c] = o;
    }
}

// ---------------------------------------------------------------------------
// MFMA retention: Q split hi/lo (2-term QK^T), K/V plain bf16.
// Block = 512 thr (8 waves), s-tile 64, t-tile 64; grid (8, 32).
// ---------------------------------------------------------------------------
__global__ __launch_bounds__(512) void retention_mfma_kernel(
    const short* __restrict__ Qhi, const short* __restrict__ Qlo,
    const short* __restrict__ Kb, const short* __restrict__ Vtb,
    float* __restrict__ Y /* ld 8192 */) {
    __shared__ short Klds[8192];    // [kblk 16][t 64][8]  (t XOR-swizzled)
    __shared__ short Vlds[8192];    // [tblk 8][v 128][8]  (v XOR-swizzled)
    __shared__ short Slds[8 * 544]; // [tblk 8][s 64][8], padded stride 544

    int tid = threadIdx.x;
    int w = tid >> 6, lane = tid & 63;
    int lr = lane & 15, lk = lane >> 4;
    int bn = blockIdx.y;
    int b = bn >> 4, n = bn & 15;

    const float l0 = -3.4657359027997265f;
    const float l1 = -6.2383246250395077f;
    float gamma = 1.0f - expf(l0 + (l1 - l0) * (float)n * (1.0f / 15.0f));
    float log2g = log2f(gamma);

    int sh = (w & 1) * 32;
    int tq = (w >> 1) * 16;
    int vq = (w >> 1) * 32;

    for (int pass = 0; pass < 2; ++pass) {
        int sTile = pass ? (15 - (int)blockIdx.x) : (int)blockIdx.x;
        int s0 = sTile * 64;

        bf16x8 qh[2][4], ql[2][4];
#pragma unroll
        for (int m = 0; m < 2; ++m)
#pragma unroll
            for (int ks = 0; ks < 4; ++ks) {
                size_t off = (size_t)(b * S_ + s0 + sh + m * 16 + lr) * 2048
                           + n * 128 + ks * 32 + lk * 8;
                qh[m][ks] = *(const bf16x8*)&Qhi[off];
                ql[m][ks] = *(const bf16x8*)&Qlo[off];
            }

        f32x4 yacc[2][2] = {};

        for (int t0 = 0; t0 <= s0; t0 += 64) {
#pragma unroll
            for (int i = 0; i < 2; ++i) {
                int e = i * 512 + tid;
                int kb = e >> 6, traw = e & 63;
                int t = traw ^ ((kb & 3) << 1);
                size_t koff = (size_t)(b * S_ + t0 + t) * 2048 + n * 128 + kb * 8;
                gload16(Kb + koff, &Klds[(i * 512 + w * 64) * 8]);
                int tb = e >> 7, vraw = e & 127;
                int v = vraw ^ ((tb & 3) << 1);
                size_t voff = (size_t)(n * 128 + v) * 2048 + b * S_ + t0 + tb * 8;
                gload16(Vtb + voff, &Vlds[(i * 512 + w * 64) * 8]);
            }
            __syncthreads();

            f32x4 sacc[2] = {};
#pragma unroll
            for (int ks = 0; ks < 4; ++ks) {
                int kb = ks * 4 + lk;
                int entry = kb * 64 + ((tq + lr) ^ ((kb & 3) << 1));
                bf16x8 kf = *(const bf16x8*)&Klds[entry * 8];
#pragma unroll
                for (int m = 0; m < 2; ++m) {
                    sacc[m] = __builtin_amdgcn_mfma_f32_16x16x32_bf16(qh[m][ks], kf, sacc[m], 0, 0, 0);
                    sacc[m] = __builtin_amdgcn_mfma_f32_16x16x32_bf16(ql[m][ks], kf, sacc[m], 0, 0, 0);
                }
            }

            int t_loc = tq + lr;
            bool diag = (t0 == s0);
#pragma unroll
            for (int m = 0; m < 2; ++m)
#pragma unroll
                for (int i = 0; i < 4; ++i) {
                    int s_loc = sh + m * 16 + lk * 4 + i;
                    int dt = (s0 + s_loc) - (t0 + t_loc);
                    float wgt = exp2f((float)dt * log2g);
                    if (diag && dt < 0) wgt = 0.0f;
                    float val = sacc[m][i] * wgt;
                    Slds[(t_loc >> 3) * 544 + s_loc * 8 + (t_loc & 7)] = f2b(val);
                }
            __syncthreads();

#pragma unroll
            for (int kt = 0; kt < 2; ++kt) {
                int kb = kt * 4 + lk;
                bf16x8 vf[2], sf[2];
#pragma unroll
                for (int m2 = 0; m2 < 2; ++m2) {
                    int v = vq + m2 * 16 + lr;
                    vf[m2] = *(const bf16x8*)&Vlds[(kb * 128 + (v ^ ((kb & 3) << 1))) * 8];
                }
#pragma unroll
                for (int n2 = 0; n2 < 2; ++n2) {
                    int scol = sh + n2 * 16 + lr;
                    sf[n2] = *(const bf16x8*)&Slds[kb * 544 + scol * 8];
                }
#pragma unroll
                for (int m2 = 0; m2 < 2; ++m2)
#pragma unroll
                    for (int n2 = 0; n2 < 2; ++n2)
                        yacc[m2][n2] = __builtin_amdgcn_mfma_f32_16x16x32_bf16(
                            vf[m2], sf[n2], yacc[m2][n2], 0, 0, 0);
            }
            __syncthreads();
        }

#pragma unroll
        for (int m2 = 0; m2 < 2; ++m2)
#pragma unroll
            for (int n2 = 0; n2 < 2; ++n2) {
                int srow = b * S_ + s0 + sh + n2 * 16 + lr;
                int vcol = n * 128 + vq + m2 * 16 + lk * 4;
                f32x4 v = yacc[m2][n2];
                *(float4*)&Y[(size_t)srow * 8192 + vcol] =
                    make_float4(v[0], v[1], v[2], v[3]);
            }
    }
}

// ---------------------------------------------------------------------------
// GroupNorm(16x128) + SiLU gate -> split-bf16 Z. Y,G at ld 8192.
// ---------------------------------------------------------------------------
__global__ __launch_bounds__(256) void gn_gate_kernel(
    const float* __restrict__ Y, const float* __restrict__ G,
    const float* __restrict__ gnw, const float* __restrict__ gnb,
    short* __restrict__ Zhi, short* __restrict__ Zlo) {
    int row = blockIdx.x;
    int lane = threadIdx.x & 63;
    int wave = threadIdx.x >> 6;
    const float* yrow = Y + (size_t)row * 8192;
    const float* grow = G + (size_t)row * 8192;
    size_t zoff = (size_t)row * 2048;

    for (int g = wave * 4; g < wave * 4 + 4; ++g) {
        float y0 = yrow[g * 128 + lane];
        float y1 = yrow[g * 128 + 64 + lane];
        float sum = y0 + y1;
#pragma unroll
        for (int m = 32; m >= 1; m >>= 1) sum += __shfl_xor(sum, m, 64);
        float mean = sum * (1.0f / 128.0f);
        float d0 = y0 - mean, d1 = y1 - mean;
        float vs = d0 * d0 + d1 * d1;
#pragma unroll
        for (int m = 32; m >= 1; m >>= 1) vs += __shfl_xor(vs, m, 64);
        float rinv = rsqrtf(vs * (1.0f / 128.0f) + 1e-5f);
        int h0 = g * 128 + lane, h1 = h0 + 64;
        float yn0 = d0 * rinv * gnw[h0] + gnb[h0];
        float yn1 = d1 * rinv * gnw[h1] + gnb[h1];
        float gv0 = grow[h0], gv1 = grow[h1];
        float z0 = (gv0 / (1.0f + expf(-gv0))) * yn0;
        float z1 = (gv1 / (1.0f + expf(-gv1))) * yn1;
        short h, l;
        f2hilo(z0, h, l); Zhi[zoff + h0] = h; Zlo[zoff + h0] = l;
        f2hilo(z1, h, l); Zhi[zoff + h1] = h; Zlo[zoff + h1] = l;
    }
}

// ---------------------------------------------------------------------------
extern "C" void kernel_launch(void* const* d_in, const int* in_sizes, int n_in,
                              void* d_out, int out_size, void* d_ws, size_t ws_size,
                              hipStream_t stream) {
    const float* X   = (const float*)d_in[0];
    const float* W_Q = (const float*)d_in[1];
    const float* W_K = (const float*)d_in[2];
    const float* W_V = (const float*)d_in[3];
    const float* W_G = (const float*)d_in[4];
    const float* W_O = (const float*)d_in[5];
    const float* gnw = (const float*)d_in[6];
    const float* gnb = (const float*)d_in[7];
    float* out = (float*)d_out;
    float* ws  = (float*)d_ws;

    // Workspace (float offsets):
    // [0,1): Xhi/Xlo  [1,3.5): Wt bf16 (5 x 2048x2048 shorts)
    // [3.5,7.5): QKGV fp32 (ld 8192)  [7.5,8.5): Qhi/Qlo  [8.5,9): Kb
    // [9,9.5): Vtb  [9.5,+): tables.  Zhi/Zlo reuse Xhi/Xlo after projection.
    short* Xhi  = (short*)ws;
    short* Xlo  = Xhi + MATF;
    short* Wt   = (short*)(ws + MATF);              // 5*MATF shorts
    float* QKGV = ws + (MATF * 7) / 2;              // Q:0 K:2048 G:4096 V:6144
    short* Qhi  = (short*)(ws + (MATF * 15) / 2);
    short* Qlo  = Qhi + MATF;
    short* Kb   = Qlo + MATF;
    short* Vtb  = Kb + MATF;
    float* sinT   = ws + (MATF * 19) / 2;
    float* cosT   = sinT + S_ * 64;
    float* scaleT = cosT + S_ * 64;
    short* Zhi = Xhi;
    short* Zlo = Xlo;

    tables_kernel<<<256, 256, 0, stream>>>(sinT, cosT, scaleT);
    cvt_hilo_kernel<<<4096, 256, 0, stream>>>(X, Xhi, Xlo);
    cvtW5_kernel<<<dim3(64, 320), 256, 0, stream>>>(W_Q, W_K, W_G, W_V, W_O, Wt);

    // Fused Q/K/G/V projection: 2048 x 8192, 256 blocks
    gemm256p_kernel<<<dim3(32, 8), 512, 0, stream>>>(Xhi, Xlo, Wt, QKGV, 8192);

    // V^T bf16 from QKGV cols 6144..8191
    tcvt_kernel<<<dim3(64, 64), 256, 0, stream>>>(QKGV + 6144, Vtb);

    xpos_kernel<<<dim3(4096, 2), 256, 0, stream>>>(QKGV, Qhi, Qlo, Kb, sinT, cosT, scaleT);

    // Retention: Y -> QKGV cols 0..2047 (Q fp32 dead after xpos)
    retention_mfma_kernel<<<dim3(8, 32), 512, 0, stream>>>(Qhi, Qlo, Kb, Vtb, QKGV);

    gn_gate_kernel<<<BS_, 256, 0, stream>>>(QKGV, QKGV + 4096, gnw, gnb, Zhi, Zlo);

    // Output GEMM: 2048x2048, 256 blocks
    gemm128p_kernel<<<dim3(16, 16), 256, 0, stream>>>(Zhi, Zlo, Wt + (size_t)8192 * 2048, out, 2048);
}